// Round 1
// baseline (402.840 us; speedup 1.0000x reference)
//
#include <hip/hip_runtime.h>
#include <math.h>

// Dims: B=8, N=8, T=512, L=512, d=256, H=8, dk=32
// ts_c=64, ts_e=192, aux_c=16, aux_e=64, edge_c=8

// ---------------- K0: PE table (512 x 256) ----------------
__global__ void pe_kernel(float* __restrict__ pe) {
    int t = blockIdx.x, dd = threadIdx.x;
    int i = dd >> 1;
    float div = expf((float)(2 * i) * (-9.210340371976184f / 256.0f));
    float ang = (float)t * div;
    pe[t * 256 + dd] = (dd & 1) ? cosf(ang) : sinf(ang);
}

// ---------------- K1: kv = [ts_emb | aux_emb] + pe ----------------
// grid (64 = B*N, 8 l-chunks), block 256 (one output column e each)
__global__ __launch_bounds__(256) void kv_kernel(
    const float* __restrict__ nbr_ts, const float* __restrict__ nbr_aux,
    const float* __restrict__ Wts, const float* __restrict__ bts,
    const float* __restrict__ Waux, const float* __restrict__ baux,
    const float* __restrict__ pe, float* __restrict__ kv) {
    __shared__ __align__(16) float ts_s[64][64];
    __shared__ __align__(16) float ax_s[16][64];
    int bn = blockIdx.x;
    int l0 = blockIdx.y * 64;
    int tid = threadIdx.x;

    const float* tsb = nbr_ts + (size_t)bn * 64 * 512;
#pragma unroll
    for (int it = 0; it < 4; ++it) {
        int idx = tid + it * 256;          // float4 index, 1024 total
        int c = idx >> 4;
        int l4 = (idx & 15) * 4;
        *(float4*)&ts_s[c][l4] = *(const float4*)&tsb[(size_t)c * 512 + l0 + l4];
    }
    const float* axb = nbr_aux + (size_t)bn * 16 * 512;
    {
        int c = tid >> 4;
        int l4 = (tid & 15) * 4;
        *(float4*)&ax_s[c][l4] = *(const float4*)&axb[(size_t)c * 512 + l0 + l4];
    }
    __syncthreads();

    int e = tid;
    float* kvb = kv + ((size_t)bn * 512 + l0) * 256;
    if (e < 192) {
        float w[64];
#pragma unroll
        for (int c4 = 0; c4 < 16; ++c4) {
            float4 t4 = *(const float4*)&Wts[e * 64 + c4 * 4];
            w[c4 * 4 + 0] = t4.x; w[c4 * 4 + 1] = t4.y;
            w[c4 * 4 + 2] = t4.z; w[c4 * 4 + 3] = t4.w;
        }
        float bias = bts[e];
        for (int l = 0; l < 64; l += 4) {
            float a0 = 0.f, a1 = 0.f, a2 = 0.f, a3 = 0.f;
#pragma unroll
            for (int c = 0; c < 64; ++c) {
                float4 dv = *(const float4*)&ts_s[c][l];
                a0 = fmaf(w[c], dv.x, a0); a1 = fmaf(w[c], dv.y, a1);
                a2 = fmaf(w[c], dv.z, a2); a3 = fmaf(w[c], dv.w, a3);
            }
            int lg = l0 + l;
            kvb[(size_t)(l + 0) * 256 + e] = a0 + bias + pe[(lg + 0) * 256 + e];
            kvb[(size_t)(l + 1) * 256 + e] = a1 + bias + pe[(lg + 1) * 256 + e];
            kvb[(size_t)(l + 2) * 256 + e] = a2 + bias + pe[(lg + 2) * 256 + e];
            kvb[(size_t)(l + 3) * 256 + e] = a3 + bias + pe[(lg + 3) * 256 + e];
        }
    } else {
        int e2 = e - 192;
        float w[16];
#pragma unroll
        for (int c4 = 0; c4 < 4; ++c4) {
            float4 t4 = *(const float4*)&Waux[e2 * 16 + c4 * 4];
            w[c4 * 4 + 0] = t4.x; w[c4 * 4 + 1] = t4.y;
            w[c4 * 4 + 2] = t4.z; w[c4 * 4 + 3] = t4.w;
        }
        float bias = baux[e2];
        for (int l = 0; l < 64; l += 4) {
            float a0 = 0.f, a1 = 0.f, a2 = 0.f, a3 = 0.f;
#pragma unroll
            for (int c = 0; c < 16; ++c) {
                float4 dv = *(const float4*)&ax_s[c][l];
                a0 = fmaf(w[c], dv.x, a0); a1 = fmaf(w[c], dv.y, a1);
                a2 = fmaf(w[c], dv.z, a2); a3 = fmaf(w[c], dv.w, a3);
            }
            int lg = l0 + l;
            kvb[(size_t)(l + 0) * 256 + e] = a0 + bias + pe[(lg + 0) * 256 + e];
            kvb[(size_t)(l + 1) * 256 + e] = a1 + bias + pe[(lg + 1) * 256 + e];
            kvb[(size_t)(l + 2) * 256 + e] = a2 + bias + pe[(lg + 2) * 256 + e];
            kvb[(size_t)(l + 3) * 256 + e] = a3 + bias + pe[(lg + 3) * 256 + e];
        }
    }
}

// ---------------- K2: x_pe + LayerNorm (ddof=1) ----------------
// grid B*T = 4096, block 256
__global__ __launch_bounds__(256) void ln_kernel(
    const float* __restrict__ x, const float* __restrict__ pe,
    const float* __restrict__ ln_a, const float* __restrict__ ln_b,
    float* __restrict__ xpe, float* __restrict__ qin) {
    int row = blockIdx.x;
    int t = row & 511;
    int tid = threadIdx.x;
    float v = x[(size_t)row * 256 + tid] + pe[t * 256 + tid];
    xpe[(size_t)row * 256 + tid] = v;

    __shared__ float red[4];
    float s = v;
#pragma unroll
    for (int off = 32; off > 0; off >>= 1) s += __shfl_xor(s, off);
    if ((tid & 63) == 0) red[tid >> 6] = s;
    __syncthreads();
    float mu = (red[0] + red[1] + red[2] + red[3]) * (1.0f / 256.0f);
    float dv = v - mu;
    float s2 = dv * dv;
#pragma unroll
    for (int off = 32; off > 0; off >>= 1) s2 += __shfl_xor(s2, off);
    __syncthreads();
    if ((tid & 63) == 0) red[tid >> 6] = s2;
    __syncthreads();
    float var = (red[0] + red[1] + red[2] + red[3]) * (1.0f / 255.0f);
    float sd = sqrtf(var);
    qin[(size_t)row * 256 + tid] = ln_a[tid] * dv / (sd + 1e-6f) + ln_b[tid];
}

// ---------------- tiled f32 GEMM: C[M x 256] = A[M x 256] @ W^T + bias ----------------
// W row-major (256 out, 256 in). grid (M/64, 4), block 256, 4x4 per thread.
__global__ __launch_bounds__(256) void gemm_f32(
    const float* __restrict__ A, const float* __restrict__ W,
    const float* __restrict__ bias, float* __restrict__ C) {
    __shared__ __align__(16) float As[32][68];
    __shared__ __align__(16) float Bs[32][68];
    int tid = threadIdx.x;
    int row0 = blockIdx.x * 64, col0 = blockIdx.y * 64;
    int tx = tid & 15, ty = tid >> 4;
    float acc[4][4] = {};
    for (int k0 = 0; k0 < 256; k0 += 32) {
#pragma unroll
        for (int it = 0; it < 2; ++it) {
            int idx = tid + it * 256;
            int m = idx >> 3;
            int kk = (idx & 7) * 4;
            float4 a = *(const float4*)&A[(size_t)(row0 + m) * 256 + k0 + kk];
            As[kk + 0][m] = a.x; As[kk + 1][m] = a.y;
            As[kk + 2][m] = a.z; As[kk + 3][m] = a.w;
            float4 b = *(const float4*)&W[(size_t)(col0 + m) * 256 + k0 + kk];
            Bs[kk + 0][m] = b.x; Bs[kk + 1][m] = b.y;
            Bs[kk + 2][m] = b.z; Bs[kk + 3][m] = b.w;
        }
        __syncthreads();
#pragma unroll
        for (int kk = 0; kk < 32; ++kk) {
            float4 av = *(const float4*)&As[kk][ty * 4];
            float4 bv = *(const float4*)&Bs[kk][tx * 4];
            float a_[4] = {av.x, av.y, av.z, av.w};
            float b_[4] = {bv.x, bv.y, bv.z, bv.w};
#pragma unroll
            for (int i = 0; i < 4; ++i)
#pragma unroll
                for (int j = 0; j < 4; ++j)
                    acc[i][j] = fmaf(a_[i], b_[j], acc[i][j]);
        }
        __syncthreads();
    }
#pragma unroll
    for (int i = 0; i < 4; ++i) {
        size_t r = row0 + ty * 4 + i;
        int c = col0 + tx * 4;
        float4 o;
        o.x = acc[i][0] + bias[c + 0];
        o.y = acc[i][1] + bias[c + 1];
        o.z = acc[i][2] + bias[c + 2];
        o.w = acc[i][3] + bias[c + 3];
        *(float4*)&C[r * 256 + c] = o;
    }
}

// ---------------- K4: fused attention per (b,n,h) ----------------
// block 256 threads; thread owns rows t=tid and t=tid+256. No-max softmax.
__global__ __launch_bounds__(256) void attn_kernel(
    const float* __restrict__ Q, const float* __restrict__ K,
    const float* __restrict__ V, const int* __restrict__ mask,
    float* __restrict__ ctx) {
    __shared__ __align__(16) float S[64 * 36];
    __shared__ __align__(16) float SV[64 * 36];
    __shared__ int ms[64];
    int tid = threadIdx.x;
    int bnh = blockIdx.x;
    int h = bnh & 7;
    int bn = bnh >> 3;
    int b = bn >> 3;
    const float* qbase = Q + ((size_t)b * 512) * 256 + h * 32;

    float q0[32], q1[32], c0[32], c1[32];
#pragma unroll
    for (int d4 = 0; d4 < 8; ++d4) {
        float4 a = *(const float4*)&qbase[(size_t)tid * 256 + d4 * 4];
        q0[4 * d4 + 0] = a.x; q0[4 * d4 + 1] = a.y;
        q0[4 * d4 + 2] = a.z; q0[4 * d4 + 3] = a.w;
        float4 bb = *(const float4*)&qbase[(size_t)(tid + 256) * 256 + d4 * 4];
        q1[4 * d4 + 0] = bb.x; q1[4 * d4 + 1] = bb.y;
        q1[4 * d4 + 2] = bb.z; q1[4 * d4 + 3] = bb.w;
    }
#pragma unroll
    for (int i = 0; i < 32; ++i) { c0[i] = 0.f; c1[i] = 0.f; }
    float sum0 = 0.f, sum1 = 0.f;
    const float scale = 0.17677669529663687f;  // 1/sqrt(32)
    const float* kb = K + (size_t)bn * 512 * 256 + h * 32;
    const float* vb = V + (size_t)bn * 512 * 256 + h * 32;

    for (int l0 = 0; l0 < 512; l0 += 64) {
#pragma unroll
        for (int it = 0; it < 2; ++it) {
            int idx = tid + it * 256;
            int ll = idx >> 3;
            int d4 = (idx & 7) * 4;
            size_t go = (size_t)(l0 + ll) * 256 + d4;
            *(float4*)&S[ll * 36 + d4] = *(const float4*)&kb[go];
            *(float4*)&SV[ll * 36 + d4] = *(const float4*)&vb[go];
        }
        if (tid < 64) ms[tid] = mask[bn * 512 + l0 + tid];
        __syncthreads();
        for (int ll = 0; ll < 64; ++ll) {
            if (ms[ll]) {
                float s0 = 0.f, s1 = 0.f;
#pragma unroll
                for (int d4 = 0; d4 < 8; ++d4) {
                    float4 k4 = *(const float4*)&S[ll * 36 + d4 * 4];
                    s0 = fmaf(q0[4 * d4 + 0], k4.x, s0);
                    s0 = fmaf(q0[4 * d4 + 1], k4.y, s0);
                    s0 = fmaf(q0[4 * d4 + 2], k4.z, s0);
                    s0 = fmaf(q0[4 * d4 + 3], k4.w, s0);
                    s1 = fmaf(q1[4 * d4 + 0], k4.x, s1);
                    s1 = fmaf(q1[4 * d4 + 1], k4.y, s1);
                    s1 = fmaf(q1[4 * d4 + 2], k4.z, s1);
                    s1 = fmaf(q1[4 * d4 + 3], k4.w, s1);
                }
                float p0 = __expf(s0 * scale), p1 = __expf(s1 * scale);
                sum0 += p0; sum1 += p1;
#pragma unroll
                for (int d4 = 0; d4 < 8; ++d4) {
                    float4 v4 = *(const float4*)&SV[ll * 36 + d4 * 4];
                    c0[4 * d4 + 0] = fmaf(p0, v4.x, c0[4 * d4 + 0]);
                    c0[4 * d4 + 1] = fmaf(p0, v4.y, c0[4 * d4 + 1]);
                    c0[4 * d4 + 2] = fmaf(p0, v4.z, c0[4 * d4 + 2]);
                    c0[4 * d4 + 3] = fmaf(p0, v4.w, c0[4 * d4 + 3]);
                    c1[4 * d4 + 0] = fmaf(p1, v4.x, c1[4 * d4 + 0]);
                    c1[4 * d4 + 1] = fmaf(p1, v4.y, c1[4 * d4 + 1]);
                    c1[4 * d4 + 2] = fmaf(p1, v4.z, c1[4 * d4 + 2]);
                    c1[4 * d4 + 3] = fmaf(p1, v4.w, c1[4 * d4 + 3]);
                }
            }
        }
        __syncthreads();
    }
    float inv0 = 1.0f / sum0, inv1 = 1.0f / sum1;
#pragma unroll
    for (int i = 0; i < 32; ++i) { c0[i] *= inv0; c1[i] *= inv1; }

    // staged coalesced write-back via LDS (reuse S), 8 batches of 64 rows
    float* cg = ctx + (size_t)bn * 512 * 256 + h * 32;
    for (int rb = 0; rb < 8; ++rb) {
        int r0 = rb * 64;
        if (rb < 4) {
            if (tid >= r0 && tid < r0 + 64) {
                int r = tid - r0;
#pragma unroll
                for (int i4 = 0; i4 < 8; ++i4) {
                    float4 o = {c0[i4 * 4 + 0], c0[i4 * 4 + 1],
                                c0[i4 * 4 + 2], c0[i4 * 4 + 3]};
                    *(float4*)&S[r * 36 + i4 * 4] = o;
                }
            }
        } else {
            int rr = r0 - 256;
            if (tid >= rr && tid < rr + 64) {
                int r = tid - rr;
#pragma unroll
                for (int i4 = 0; i4 < 8; ++i4) {
                    float4 o = {c1[i4 * 4 + 0], c1[i4 * 4 + 1],
                                c1[i4 * 4 + 2], c1[i4 * 4 + 3]};
                    *(float4*)&S[r * 36 + i4 * 4] = o;
                }
            }
        }
        __syncthreads();
#pragma unroll
        for (int it = 0; it < 2; ++it) {
            int idx = tid + it * 256;
            int ll = idx >> 3;
            int d4 = (idx & 7) * 4;
            *(float4*)&cg[(size_t)(r0 + ll) * 256 + d4] =
                *(const float4*)&S[ll * 36 + d4];
        }
        __syncthreads();
    }
}

// ---------------- K5: out = mean_n (x_pe + attn) * edge ----------------
// grid B*T = 4096, block 256
__global__ __launch_bounds__(256) void final_kernel(
    const float* __restrict__ xpe, const float* __restrict__ attn,
    const float* __restrict__ nbr_edge, const float* __restrict__ Wedge,
    const float* __restrict__ bedge, float* __restrict__ out) {
    int row = blockIdx.x;  // b*512 + t
    int tid = threadIdx.x;
    int b = row >> 9, t = row & 511;
    float xp = xpe[(size_t)row * 256 + tid];
    float we[8];
#pragma unroll
    for (int c = 0; c < 8; ++c) we[c] = Wedge[tid * 8 + c];
    float be = bedge[tid];
    float acc = 0.f;
#pragma unroll
    for (int n = 0; n < 8; ++n) {
        size_t bn = (size_t)(b * 8 + n);
        float av = attn[(bn * 512 + t) * 256 + tid];
        float eg = be;
#pragma unroll
        for (int c = 0; c < 8; ++c)
            eg = fmaf(nbr_edge[(bn * 8 + c) * 512 + t], we[c], eg);
        acc = fmaf(xp + av, eg, acc);
    }
    out[(size_t)row * 256 + tid] = acc * 0.125f;
}

extern "C" void kernel_launch(void* const* d_in, const int* in_sizes, int n_in,
                              void* d_out, int out_size, void* d_ws, size_t ws_size,
                              hipStream_t stream) {
    const float* x        = (const float*)d_in[0];
    const float* nbr_ts   = (const float*)d_in[1];
    const float* nbr_aux  = (const float*)d_in[2];
    const float* nbr_edge = (const float*)d_in[3];
    const int*   mask     = (const int*)d_in[4];
    const float* Wts  = (const float*)d_in[5];
    const float* bts  = (const float*)d_in[6];
    const float* Waux = (const float*)d_in[7];
    const float* baux = (const float*)d_in[8];
    const float* Wedge= (const float*)d_in[9];
    const float* bedge= (const float*)d_in[10];
    const float* ln_a = (const float*)d_in[11];
    const float* ln_b = (const float*)d_in[12];
    const float* Wq = (const float*)d_in[13];
    const float* bq = (const float*)d_in[14];
    const float* Wk = (const float*)d_in[15];
    const float* bk = (const float*)d_in[16];
    const float* Wv = (const float*)d_in[17];
    const float* bv = (const float*)d_in[18];
    const float* Wo = (const float*)d_in[19];
    const float* bo = (const float*)d_in[20];
    float* out = (float*)d_out;

    float* ws   = (float*)d_ws;
    float* pe   = ws;                    // 131072
    float* xpe  = pe + 131072;           // 1048576
    float* qin  = xpe + 1048576;         // 1048576
    float* q    = qin + 1048576;         // 1048576
    float* bufA = q + 1048576;           // 8388608  (kv -> ctx)
    float* bufB = bufA + 8388608;        // 8388608  (k  -> attn)
    float* bufC = bufB + 8388608;        // 8388608  (v)

    pe_kernel<<<512, 256, 0, stream>>>(pe);
    kv_kernel<<<dim3(64, 8), 256, 0, stream>>>(nbr_ts, nbr_aux, Wts, bts,
                                               Waux, baux, pe, bufA);
    ln_kernel<<<4096, 256, 0, stream>>>(x, pe, ln_a, ln_b, xpe, qin);
    gemm_f32<<<dim3(16, 4), 256, 0, stream>>>(qin, Wq, bq, q);
    gemm_f32<<<dim3(512, 4), 256, 0, stream>>>(bufA, Wk, bk, bufB);
    gemm_f32<<<dim3(512, 4), 256, 0, stream>>>(bufA, Wv, bv, bufC);
    attn_kernel<<<512, 256, 0, stream>>>(q, bufB, bufC, mask, bufA);
    gemm_f32<<<dim3(512, 4), 256, 0, stream>>>(bufA, Wo, bo, bufB);
    final_kernel<<<4096, 256, 0, stream>>>(xpe, bufB, nbr_edge, Wedge, bedge, out);
}

// Round 2
// 170.402 us; speedup vs baseline: 2.3641x; 2.3641x over previous
//
#include <hip/hip_runtime.h>
#include <hip/hip_bf16.h>
#include <math.h>

// Dims: B=8, N=8, T=512, L=512, d=256, H=8, dk=32
typedef __attribute__((ext_vector_type(8))) short bf16x8;
typedef __attribute__((ext_vector_type(4))) short bf16x4;
typedef __attribute__((ext_vector_type(4))) float f32x4;

__device__ __forceinline__ short f2bf(float f) {
    return (short)__builtin_bit_cast(unsigned short, __float2bfloat16(f));
}

#if defined(__has_builtin)
#if __has_builtin(__builtin_amdgcn_mfma_f32_16x16x16bf16_1k)
#define HAVE_MFMA16 1
#endif
#endif

__device__ __forceinline__ f32x4 mfma16(bf16x4 a, bf16x4 b, f32x4 c) {
#ifdef HAVE_MFMA16
    return __builtin_amdgcn_mfma_f32_16x16x16bf16_1k(a, b, c, 0, 0, 0);
#else
    f32x4 d;
    asm volatile("v_mfma_f32_16x16x16_bf16 %0, %1, %2, %3"
                 : "=v"(d) : "v"(a), "v"(b), "v"(c));
    return d;
#endif
}

// ---------------- K0: PE table (512 x 256) f32 ----------------
__global__ void pe_kernel(float* __restrict__ pe) {
    int t = blockIdx.x, dd = threadIdx.x;
    int i = dd >> 1;
    float div = expf((float)(2 * i) * (-9.210340371976184f / 256.0f));
    float ang = (float)t * div;
    pe[t * 256 + dd] = (dd & 1) ? cosf(ang) : sinf(ang);
}

// ---------------- weights -> bf16 ----------------
__global__ __launch_bounds__(256) void wconv_kernel(
    const float* __restrict__ Wq, const float* __restrict__ Wk,
    const float* __restrict__ Wv, const float* __restrict__ Wo,
    short* __restrict__ out) {
    int i = blockIdx.x * 256 + threadIdx.x;   // 65536 per matrix
    out[i]          = f2bf(Wq[i]);
    out[65536 + i]  = f2bf(Wk[i]);
    out[131072 + i] = f2bf(Wv[i]);
    out[196608 + i] = f2bf(Wo[i]);
}

// ---------------- K1: kv = [ts_emb | aux_emb] + pe  (bf16 out) ----------------
__global__ __launch_bounds__(256) void kv_kernel(
    const float* __restrict__ nbr_ts, const float* __restrict__ nbr_aux,
    const float* __restrict__ Wts, const float* __restrict__ bts,
    const float* __restrict__ Waux, const float* __restrict__ baux,
    const float* __restrict__ pe, short* __restrict__ kv) {
    __shared__ __align__(16) float ts_s[64][64];
    __shared__ __align__(16) float ax_s[16][64];
    __shared__ __align__(16) short out_s[64 * 256];
    int bn = blockIdx.x;
    int l0 = blockIdx.y * 64;
    int tid = threadIdx.x;

    const float* tsb = nbr_ts + (size_t)bn * 64 * 512;
#pragma unroll
    for (int it = 0; it < 4; ++it) {
        int idx = tid + it * 256;
        int c = idx >> 4;
        int l4 = (idx & 15) * 4;
        *(float4*)&ts_s[c][l4] = *(const float4*)&tsb[(size_t)c * 512 + l0 + l4];
    }
    const float* axb = nbr_aux + (size_t)bn * 16 * 512;
    {
        int c = tid >> 4;
        int l4 = (tid & 15) * 4;
        *(float4*)&ax_s[c][l4] = *(const float4*)&axb[(size_t)c * 512 + l0 + l4];
    }
    __syncthreads();

    int e = tid;
    if (e < 192) {
        float w[64];
#pragma unroll
        for (int c4 = 0; c4 < 16; ++c4) {
            float4 t4 = *(const float4*)&Wts[e * 64 + c4 * 4];
            w[c4 * 4 + 0] = t4.x; w[c4 * 4 + 1] = t4.y;
            w[c4 * 4 + 2] = t4.z; w[c4 * 4 + 3] = t4.w;
        }
        float bias = bts[e];
        for (int l = 0; l < 64; l += 4) {
            float a0 = 0.f, a1 = 0.f, a2 = 0.f, a3 = 0.f;
#pragma unroll
            for (int c = 0; c < 64; ++c) {
                float4 dv = *(const float4*)&ts_s[c][l];
                a0 = fmaf(w[c], dv.x, a0); a1 = fmaf(w[c], dv.y, a1);
                a2 = fmaf(w[c], dv.z, a2); a3 = fmaf(w[c], dv.w, a3);
            }
            int lg = l0 + l;
            out_s[(l + 0) * 256 + e] = f2bf(a0 + bias + pe[(lg + 0) * 256 + e]);
            out_s[(l + 1) * 256 + e] = f2bf(a1 + bias + pe[(lg + 1) * 256 + e]);
            out_s[(l + 2) * 256 + e] = f2bf(a2 + bias + pe[(lg + 2) * 256 + e]);
            out_s[(l + 3) * 256 + e] = f2bf(a3 + bias + pe[(lg + 3) * 256 + e]);
        }
    } else {
        int e2 = e - 192;
        float w[16];
#pragma unroll
        for (int c4 = 0; c4 < 4; ++c4) {
            float4 t4 = *(const float4*)&Waux[e2 * 16 + c4 * 4];
            w[c4 * 4 + 0] = t4.x; w[c4 * 4 + 1] = t4.y;
            w[c4 * 4 + 2] = t4.z; w[c4 * 4 + 3] = t4.w;
        }
        float bias = baux[e2];
        for (int l = 0; l < 64; l += 4) {
            float a0 = 0.f, a1 = 0.f, a2 = 0.f, a3 = 0.f;
#pragma unroll
            for (int c = 0; c < 16; ++c) {
                float4 dv = *(const float4*)&ax_s[c][l];
                a0 = fmaf(w[c], dv.x, a0); a1 = fmaf(w[c], dv.y, a1);
                a2 = fmaf(w[c], dv.z, a2); a3 = fmaf(w[c], dv.w, a3);
            }
            int lg = l0 + l;
            out_s[(l + 0) * 256 + e] = f2bf(a0 + bias + pe[(lg + 0) * 256 + e]);
            out_s[(l + 1) * 256 + e] = f2bf(a1 + bias + pe[(lg + 1) * 256 + e]);
            out_s[(l + 2) * 256 + e] = f2bf(a2 + bias + pe[(lg + 2) * 256 + e]);
            out_s[(l + 3) * 256 + e] = f2bf(a3 + bias + pe[(lg + 3) * 256 + e]);
        }
    }
    __syncthreads();
    // coalesced bf16 write
#pragma unroll
    for (int it = 0; it < 8; ++it) {
        int idx = tid + it * 256;
        int l = idx >> 5, ch = idx & 31;
        *(bf16x8*)&kv[((size_t)(bn * 512 + l0 + l)) * 256 + ch * 8] =
            *(const bf16x8*)&out_s[l * 256 + ch * 8];
    }
}

// ---------------- K2: x_pe + LayerNorm (ddof=1), bf16 qin ----------------
__global__ __launch_bounds__(256) void ln_kernel(
    const float* __restrict__ x, const float* __restrict__ pe,
    const float* __restrict__ ln_a, const float* __restrict__ ln_b,
    float* __restrict__ xpe, short* __restrict__ qin) {
    int row = blockIdx.x;
    int t = row & 511;
    int tid = threadIdx.x;
    float v = x[(size_t)row * 256 + tid] + pe[t * 256 + tid];
    xpe[(size_t)row * 256 + tid] = v;

    __shared__ float red[4];
    float s = v;
#pragma unroll
    for (int off = 32; off > 0; off >>= 1) s += __shfl_xor(s, off);
    if ((tid & 63) == 0) red[tid >> 6] = s;
    __syncthreads();
    float mu = (red[0] + red[1] + red[2] + red[3]) * (1.0f / 256.0f);
    float dv = v - mu;
    float s2 = dv * dv;
#pragma unroll
    for (int off = 32; off > 0; off >>= 1) s2 += __shfl_xor(s2, off);
    __syncthreads();
    if ((tid & 63) == 0) red[tid >> 6] = s2;
    __syncthreads();
    float var = (red[0] + red[1] + red[2] + red[3]) * (1.0f / 255.0f);
    float sd = sqrtf(var);
    qin[(size_t)row * 256 + tid] = f2bf(ln_a[tid] * dv / (sd + 1e-6f) + ln_b[tid]);
}

// ---------------- bf16 MFMA GEMM: C[M x 256] = A[M x 256] @ W^T + bias ----------------
// tile 128x128, 4 waves (2x2), wave 64x64 = 4x4 fragments, K-step 32.
template <int OUT_BF>
__global__ __launch_bounds__(256) void gemm_bf16(
    const short* __restrict__ A, const short* __restrict__ W,
    const float* __restrict__ bias, void* __restrict__ Cout) {
    __shared__ short As[128 * 40];
    __shared__ short Bs[128 * 40];
    int tid = threadIdx.x;
    int row0 = blockIdx.x * 128, col0 = blockIdx.y * 128;
    int wid = tid >> 6, lane = tid & 63;
    int wm = wid >> 1, wn = wid & 1;
    int g = lane >> 4, c = lane & 15;
    f32x4 acc[4][4];
#pragma unroll
    for (int i = 0; i < 4; ++i)
#pragma unroll
        for (int j = 0; j < 4; ++j) acc[i][j] = (f32x4){0.f, 0.f, 0.f, 0.f};

    for (int k0 = 0; k0 < 256; k0 += 32) {
#pragma unroll
        for (int it = 0; it < 2; ++it) {
            int idx = tid + it * 256;
            int r = idx >> 2, ch = idx & 3;
            *(bf16x8*)&As[r * 40 + ch * 8] =
                *(const bf16x8*)&A[(size_t)(row0 + r) * 256 + k0 + ch * 8];
            *(bf16x8*)&Bs[r * 40 + ch * 8] =
                *(const bf16x8*)&W[(size_t)(col0 + r) * 256 + k0 + ch * 8];
        }
        __syncthreads();
        bf16x8 af[4], bfr[4];
#pragma unroll
        for (int mf = 0; mf < 4; ++mf)
            af[mf] = *(const bf16x8*)&As[(wm * 64 + mf * 16 + c) * 40 + g * 8];
#pragma unroll
        for (int nf = 0; nf < 4; ++nf)
            bfr[nf] = *(const bf16x8*)&Bs[(wn * 64 + nf * 16 + c) * 40 + g * 8];
#pragma unroll
        for (int mf = 0; mf < 4; ++mf)
#pragma unroll
            for (int nf = 0; nf < 4; ++nf)
                acc[mf][nf] = __builtin_amdgcn_mfma_f32_16x16x32_bf16(
                    af[mf], bfr[nf], acc[mf][nf], 0, 0, 0);
        __syncthreads();
    }
    short* Cb = (short*)Cout;
    float* Cf = (float*)Cout;
#pragma unroll
    for (int nf = 0; nf < 4; ++nf) {
        int col = col0 + wn * 64 + nf * 16 + c;
        float bz = bias[col];
#pragma unroll
        for (int mf = 0; mf < 4; ++mf)
#pragma unroll
            for (int r = 0; r < 4; ++r) {
                int row = row0 + wm * 64 + mf * 16 + g * 4 + r;
                float v = acc[mf][nf][r] + bz;
                if (OUT_BF) Cb[(size_t)row * 256 + col] = f2bf(v);
                else        Cf[(size_t)row * 256 + col] = v;
            }
    }
}

// ---------------- K4: fused MFMA attention per (b,n,h) ----------------
// 4 waves; wave owns 128 t rows (8 t-frags of 16).
// S^T = mfma_16x16x32(K_frag, Q_frag): lane holds P^T in exactly the
// A-fragment layout of mfma_16x16x16 -> softmax fully in-register.
__global__ __launch_bounds__(256, 2) void attn_kernel(
    const short* __restrict__ Q, const short* __restrict__ K,
    const short* __restrict__ V, const int* __restrict__ mask,
    short* __restrict__ ctx) {
    __shared__ short K_lds[512 * 40];   // rows padded to 80B
    __shared__ short V_lds[512 * 36];   // rows padded to 72B
    __shared__ float mb_lds[512];       // 0 or -1e9 bias
    int tid = threadIdx.x;
    int bx = blockIdx.x;
    int h = bx & 7, bn = bx >> 3, b = bn >> 3;
    size_t kvbase = (size_t)bn * 512 * 256 + h * 32;
    const short* kg = K + kvbase;
    const short* vg = V + kvbase;
#pragma unroll
    for (int it = 0; it < 8; ++it) {
        int idx = tid + it * 256;
        int l = idx >> 2, ch = idx & 3;
        bf16x8 kval = *(const bf16x8*)&kg[(size_t)l * 256 + ch * 8];
        *(bf16x8*)&K_lds[l * 40 + ch * 8] = kval;
        bf16x8 vval = *(const bf16x8*)&vg[(size_t)l * 256 + ch * 8];
        *(bf16x4*)&V_lds[l * 36 + ch * 8]     = *((bf16x4*)&vval);
        *(bf16x4*)&V_lds[l * 36 + ch * 8 + 4] = *((bf16x4*)&vval + 1);
    }
    mb_lds[tid]       = mask[bn * 512 + tid]       ? 0.f : -1e9f;
    mb_lds[tid + 256] = mask[bn * 512 + tid + 256] ? 0.f : -1e9f;
    __syncthreads();

    int wid = tid >> 6, lane = tid & 63;
    int g = lane >> 4, c = lane & 15;
    int t0 = wid * 128;
    const short* qg = Q + ((size_t)b * 512 + t0 + c) * 256 + h * 32 + g * 8;
    bf16x8 qf[8];
#pragma unroll
    for (int tf = 0; tf < 8; ++tf)
        qf[tf] = *(const bf16x8*)&qg[(size_t)tf * 16 * 256];

    f32x4 ctxa[8][2];
    float rs[8];
#pragma unroll
    for (int tf = 0; tf < 8; ++tf) {
        ctxa[tf][0] = (f32x4){0.f, 0.f, 0.f, 0.f};
        ctxa[tf][1] = (f32x4){0.f, 0.f, 0.f, 0.f};
        rs[tf] = 0.f;
    }
    const float SCALE2 = 0.25503482f;   // (1/sqrt(32)) * log2(e)

    for (int l0 = 0; l0 < 512; l0 += 16) {
        bf16x8 ak = *(const bf16x8*)&K_lds[(l0 + c) * 40 + g * 8];
        bf16x4 vb[2];
#pragma unroll
        for (int df = 0; df < 2; ++df)
#pragma unroll
            for (int j = 0; j < 4; ++j)
                vb[df][j] = V_lds[(l0 + g * 4 + j) * 36 + df * 16 + c];
        float mb[4];
#pragma unroll
        for (int r = 0; r < 4; ++r) mb[r] = mb_lds[l0 + g * 4 + r];
#pragma unroll
        for (int tf = 0; tf < 8; ++tf) {
            f32x4 s = __builtin_amdgcn_mfma_f32_16x16x32_bf16(
                ak, qf[tf], (f32x4){0.f, 0.f, 0.f, 0.f}, 0, 0, 0);
            float p0 = exp2f(fmaf(s[0], SCALE2, mb[0]));
            float p1 = exp2f(fmaf(s[1], SCALE2, mb[1]));
            float p2 = exp2f(fmaf(s[2], SCALE2, mb[2]));
            float p3 = exp2f(fmaf(s[3], SCALE2, mb[3]));
            rs[tf] += (p0 + p1) + (p2 + p3);
            bf16x4 pa;
            pa[0] = f2bf(p0); pa[1] = f2bf(p1);
            pa[2] = f2bf(p2); pa[3] = f2bf(p3);
            ctxa[tf][0] = mfma16(pa, vb[0], ctxa[tf][0]);
            ctxa[tf][1] = mfma16(pa, vb[1], ctxa[tf][1]);
        }
    }
#ifndef HAVE_MFMA16
    asm volatile("s_nop 7\ns_nop 7");
#endif
    // rowsum reduce (partial per lane over its 4 l-regs, across 4 groups)
#pragma unroll
    for (int tf = 0; tf < 8; ++tf) {
        float r = rs[tf];
        r += __shfl_xor(r, 16);
        r += __shfl_xor(r, 32);
        float inv = 1.f / r;   // rowsum for t = c, replicated over groups
#pragma unroll
        for (int rr = 0; rr < 4; ++rr) {
            float invr = __shfl(inv, (lane & 48) | (g * 4 + rr));
            ctxa[tf][0][rr] *= invr;
            ctxa[tf][1][rr] *= invr;
        }
    }
    __syncthreads();   // done reading K_lds; reuse as ctx staging [512][40]
#pragma unroll
    for (int tf = 0; tf < 8; ++tf)
#pragma unroll
        for (int df = 0; df < 2; ++df)
#pragma unroll
            for (int rr = 0; rr < 4; ++rr)
                K_lds[(t0 + tf * 16 + g * 4 + rr) * 40 + df * 16 + c] =
                    f2bf(ctxa[tf][df][rr]);
    __syncthreads();
    short* cg = ctx + kvbase;
#pragma unroll
    for (int it = 0; it < 8; ++it) {
        int idx = tid + it * 256;
        int l = idx >> 2, ch = idx & 3;
        *(bf16x8*)&cg[(size_t)l * 256 + ch * 8] =
            *(const bf16x8*)&K_lds[l * 40 + ch * 8];
    }
}

// ---------------- K5: out = mean_n (x_pe + attn) * edge ----------------
__global__ __launch_bounds__(256) void final_kernel(
    const float* __restrict__ xpe, const float* __restrict__ attn,
    const float* __restrict__ nbr_edge, const float* __restrict__ Wedge,
    const float* __restrict__ bedge, float* __restrict__ out) {
    int row = blockIdx.x;
    int tid = threadIdx.x;
    int b = row >> 9, t = row & 511;
    float xp = xpe[(size_t)row * 256 + tid];
    float we[8];
#pragma unroll
    for (int cc = 0; cc < 8; ++cc) we[cc] = Wedge[tid * 8 + cc];
    float be = bedge[tid];
    float acc = 0.f;
#pragma unroll
    for (int n = 0; n < 8; ++n) {
        size_t bn = (size_t)(b * 8 + n);
        float av = attn[(bn * 512 + t) * 256 + tid];
        float eg = be;
#pragma unroll
        for (int cc = 0; cc < 8; ++cc)
            eg = fmaf(nbr_edge[(bn * 8 + cc) * 512 + t], we[cc], eg);
        acc = fmaf(xp + av, eg, acc);
    }
    out[(size_t)row * 256 + tid] = acc * 0.125f;
}

extern "C" void kernel_launch(void* const* d_in, const int* in_sizes, int n_in,
                              void* d_out, int out_size, void* d_ws, size_t ws_size,
                              hipStream_t stream) {
    const float* x        = (const float*)d_in[0];
    const float* nbr_ts   = (const float*)d_in[1];
    const float* nbr_aux  = (const float*)d_in[2];
    const float* nbr_edge = (const float*)d_in[3];
    const int*   mask     = (const int*)d_in[4];
    const float* Wts  = (const float*)d_in[5];
    const float* bts  = (const float*)d_in[6];
    const float* Waux = (const float*)d_in[7];
    const float* baux = (const float*)d_in[8];
    const float* Wedge= (const float*)d_in[9];
    const float* bedge= (const float*)d_in[10];
    const float* ln_a = (const float*)d_in[11];
    const float* ln_b = (const float*)d_in[12];
    const float* Wq = (const float*)d_in[13];
    const float* bq = (const float*)d_in[14];
    const float* Wk = (const float*)d_in[15];
    const float* bk = (const float*)d_in[16];
    const float* Wv = (const float*)d_in[17];
    const float* bv = (const float*)d_in[18];
    const float* Wo = (const float*)d_in[19];
    const float* bo = (const float*)d_in[20];
    float* out = (float*)d_out;

    char* W = (char*)d_ws;
    float* pe_f   = (float*)(W);                  // 512 KB
    float* xpe_f  = (float*)(W + 524288);         // 4 MB
    float* attn_f = (float*)(W + 4718592);        // 32 MB
    short* qin_bf = (short*)(W + 38273024);       // 2 MB
    short* q_bf   = (short*)(W + 40370176);       // 2 MB
    short* kv_bf  = (short*)(W + 42467328);       // 16 MB
    short* k_bf   = (short*)(W + 59244544);       // 16 MB
    short* v_bf   = (short*)(W + 76021760);       // 16 MB
    short* ctx_bf = (short*)(W + 92798976);       // 16 MB
    short* w_bf   = (short*)(W + 109576192);      // 512 KB
    short* wq_bf = w_bf;
    short* wk_bf = w_bf + 65536;
    short* wv_bf = w_bf + 131072;
    short* wo_bf = w_bf + 196608;

    wconv_kernel<<<256, 256, 0, stream>>>(Wq, Wk, Wv, Wo, w_bf);
    pe_kernel<<<512, 256, 0, stream>>>(pe_f);
    kv_kernel<<<dim3(64, 8), 256, 0, stream>>>(nbr_ts, nbr_aux, Wts, bts,
                                               Waux, baux, pe_f, kv_bf);
    ln_kernel<<<4096, 256, 0, stream>>>(x, pe_f, ln_a, ln_b, xpe_f, qin_bf);
    gemm_bf16<1><<<dim3(32, 2),  256, 0, stream>>>(qin_bf, wq_bf, bq, q_bf);
    gemm_bf16<1><<<dim3(256, 2), 256, 0, stream>>>(kv_bf, wk_bf, bk, k_bf);
    gemm_bf16<1><<<dim3(256, 2), 256, 0, stream>>>(kv_bf, wv_bf, bv, v_bf);
    attn_kernel<<<512, 256, 0, stream>>>(q_bf, k_bf, v_bf, mask, ctx_bf);
    gemm_bf16<0><<<dim3(256, 2), 256, 0, stream>>>(ctx_bf, wo_bf, bo, attn_f);
    final_kernel<<<4096, 256, 0, stream>>>(xpe_f, attn_f, nbr_edge, Wedge, bedge, out);
}

// Round 3
// 155.475 us; speedup vs baseline: 2.5910x; 1.0960x over previous
//
#include <hip/hip_runtime.h>
#include <hip/hip_bf16.h>
#include <math.h>

// Dims: B=8, N=8, T=512, L=512, d=256, H=8, dk=32
typedef __attribute__((ext_vector_type(8))) short bf16x8;
typedef __attribute__((ext_vector_type(4))) short bf16x4;
typedef __attribute__((ext_vector_type(4))) float f32x4;

__device__ __forceinline__ short f2bf(float f) {
    return (short)__builtin_bit_cast(unsigned short, __float2bfloat16(f));
}

#if defined(__has_builtin)
#if __has_builtin(__builtin_amdgcn_mfma_f32_16x16x16bf16_1k)
#define HAVE_MFMA16 1
#endif
#endif

__device__ __forceinline__ f32x4 mfma16(bf16x4 a, bf16x4 b, f32x4 c) {
#ifdef HAVE_MFMA16
    return __builtin_amdgcn_mfma_f32_16x16x16bf16_1k(a, b, c, 0, 0, 0);
#else
    f32x4 d;
    asm volatile("v_mfma_f32_16x16x16_bf16 %0, %1, %2, %3"
                 : "=v"(d) : "v"(a), "v"(b), "v"(c));
    return d;
#endif
}

// ---------------- K0: PE table (512 x 256) f32 ----------------
__global__ void pe_kernel(float* __restrict__ pe) {
    int t = blockIdx.x, dd = threadIdx.x;
    int i = dd >> 1;
    float div = expf((float)(2 * i) * (-9.210340371976184f / 256.0f));
    float ang = (float)t * div;
    pe[t * 256 + dd] = (dd & 1) ? cosf(ang) : sinf(ang);
}

// ---------------- weights -> bf16 ----------------
__global__ __launch_bounds__(256) void wconv_kernel(
    const float* __restrict__ Wq, const float* __restrict__ Wk,
    const float* __restrict__ Wv, const float* __restrict__ Wo,
    short* __restrict__ out) {
    int i = blockIdx.x * 256 + threadIdx.x;   // 65536 per matrix
    out[i]          = f2bf(Wq[i]);
    out[65536 + i]  = f2bf(Wk[i]);
    out[131072 + i] = f2bf(Wv[i]);
    out[196608 + i] = f2bf(Wo[i]);
}

// ---------------- prep2: block-diagonal W2 [256][96] bf16 + bias2 ----------------
__global__ __launch_bounds__(256) void prep2_kernel(
    const float* __restrict__ Wts, const float* __restrict__ Waux,
    const float* __restrict__ bts, const float* __restrict__ baux,
    short* __restrict__ W2, float* __restrict__ bias2) {
    int idx = blockIdx.x * 256 + threadIdx.x;   // 96*256 = 24576
    int e = idx / 96, ch = idx - e * 96;
    float v = 0.f;
    if (ch < 64) { if (e < 192) v = Wts[e * 64 + ch]; }
    else if (ch < 80) { if (e >= 192) v = Waux[(e - 192) * 16 + (ch - 64)]; }
    W2[idx] = f2bf(v);
    if (idx < 256) bias2[idx] = idx < 192 ? bts[idx] : baux[idx - 192];
}

// ---------------- kv embed as MFMA GEMM over K=96 ----------------
// grid (64 bn, 4 l-blocks of 128), 512 threads (8 waves: 2 l x 4 e).
__global__ __launch_bounds__(512, 2) void kv_gemm(
    const float* __restrict__ nbr_ts, const float* __restrict__ nbr_aux,
    const short* __restrict__ W2, const float* __restrict__ bias2,
    const float* __restrict__ pe, short* __restrict__ kv) {
    __shared__ __align__(16) float S1[64 * 132];
    __shared__ __align__(16) float S2[16 * 132];
    __shared__ __align__(16) short A_lds[128 * 104];
    int tid = threadIdx.x;
    int bn = blockIdx.x, l0 = blockIdx.y * 128;
    const float* tsb = nbr_ts + (size_t)bn * 64 * 512;
    const float* axb = nbr_aux + (size_t)bn * 16 * 512;
#pragma unroll
    for (int it = 0; it < 4; ++it) {
        int idx = tid + it * 512;
        int cc = idx >> 5, lq = idx & 31;
        *(float4*)&S1[cc * 132 + lq * 4] =
            *(const float4*)&tsb[(size_t)cc * 512 + l0 + lq * 4];
    }
    {
        int cc = tid >> 5, lq = tid & 31;
        *(float4*)&S2[cc * 132 + lq * 4] =
            *(const float4*)&axb[(size_t)cc * 512 + l0 + lq * 4];
    }
    __syncthreads();
    // transpose + bf16 pack: A_lds[l][ch], ch 0..63 ts, 64..79 aux, 80..95 zero
#pragma unroll
    for (int p = 0; p < 3; ++p) {
        int tk = tid + p * 512;
        int l = tk & 127, chunk = tk >> 7;
        short v8[8];
        if (chunk < 8) {
#pragma unroll
            for (int i = 0; i < 8; ++i) v8[i] = f2bf(S1[(chunk * 8 + i) * 132 + l]);
        } else if (chunk < 10) {
#pragma unroll
            for (int i = 0; i < 8; ++i) v8[i] = f2bf(S2[((chunk - 8) * 8 + i) * 132 + l]);
        } else {
#pragma unroll
            for (int i = 0; i < 8; ++i) v8[i] = 0;
        }
        *(bf16x8*)&A_lds[l * 104 + chunk * 8] = *(bf16x8*)v8;
    }
    __syncthreads();
    int wid = tid >> 6, lane = tid & 63;
    int g = lane >> 4, c = lane & 15;
    int lm = wid >> 2, le = wid & 3;
    bf16x8 wf[4][3];
#pragma unroll
    for (int nf = 0; nf < 4; ++nf)
#pragma unroll
        for (int ks = 0; ks < 3; ++ks)
            wf[nf][ks] = *(const bf16x8*)&W2[(size_t)(le * 64 + nf * 16 + c) * 96 +
                                             ks * 32 + g * 8];
    f32x4 acc[4][4];
#pragma unroll
    for (int i = 0; i < 4; ++i)
#pragma unroll
        for (int j = 0; j < 4; ++j) acc[i][j] = (f32x4){0.f, 0.f, 0.f, 0.f};
#pragma unroll
    for (int ks = 0; ks < 3; ++ks) {
#pragma unroll
        for (int mf = 0; mf < 4; ++mf) {
            bf16x8 af = *(const bf16x8*)&A_lds[(lm * 64 + mf * 16 + c) * 104 +
                                               ks * 32 + g * 8];
#pragma unroll
            for (int nf = 0; nf < 4; ++nf)
                acc[mf][nf] = __builtin_amdgcn_mfma_f32_16x16x32_bf16(
                    af, wf[nf][ks], acc[mf][nf], 0, 0, 0);
        }
    }
    short* kvb = kv + ((size_t)bn * 512 + l0) * 256;
#pragma unroll
    for (int nf = 0; nf < 4; ++nf) {
        int e = le * 64 + nf * 16 + c;
        float b2 = bias2[e];
#pragma unroll
        for (int mf = 0; mf < 4; ++mf) {
            int lr = lm * 64 + mf * 16 + g * 4;
#pragma unroll
            for (int r = 0; r < 4; ++r) {
                float v = acc[mf][nf][r] + b2 + pe[(size_t)(l0 + lr + r) * 256 + e];
                kvb[(size_t)(lr + r) * 256 + e] = f2bf(v);
            }
        }
    }
}

// ---------------- K2: x_pe + LayerNorm (ddof=1), bf16 qin ----------------
__global__ __launch_bounds__(256) void ln_kernel(
    const float* __restrict__ x, const float* __restrict__ pe,
    const float* __restrict__ ln_a, const float* __restrict__ ln_b,
    float* __restrict__ xpe, short* __restrict__ qin) {
    int row = blockIdx.x;
    int t = row & 511;
    int tid = threadIdx.x;
    float v = x[(size_t)row * 256 + tid] + pe[t * 256 + tid];
    xpe[(size_t)row * 256 + tid] = v;

    __shared__ float red[4];
    float s = v;
#pragma unroll
    for (int off = 32; off > 0; off >>= 1) s += __shfl_xor(s, off);
    if ((tid & 63) == 0) red[tid >> 6] = s;
    __syncthreads();
    float mu = (red[0] + red[1] + red[2] + red[3]) * (1.0f / 256.0f);
    float dv = v - mu;
    float s2 = dv * dv;
#pragma unroll
    for (int off = 32; off > 0; off >>= 1) s2 += __shfl_xor(s2, off);
    __syncthreads();
    if ((tid & 63) == 0) red[tid >> 6] = s2;
    __syncthreads();
    float var = (red[0] + red[1] + red[2] + red[3]) * (1.0f / 255.0f);
    float sd = sqrtf(var);
    qin[(size_t)row * 256 + tid] = f2bf(ln_a[tid] * dv / (sd + 1e-6f) + ln_b[tid]);
}

// ---------------- bf16 MFMA GEMM: C[M x 256] = A[M x 256] @ W^T + bias ----------------
// tile 128x128, 4 waves (2x2), wave 64x64 = 4x4 fragments, K-step 32.
// LDS rows unpadded 32 elems (64B): b128 frag reads are bank-even.
template <int OUT_BF>
__global__ __launch_bounds__(256) void gemm_bf16(
    const short* __restrict__ A, const short* __restrict__ W,
    const float* __restrict__ bias, void* __restrict__ Cout) {
    __shared__ __align__(16) short As[128 * 32];
    __shared__ __align__(16) short Bs[128 * 32];
    int tid = threadIdx.x;
    int row0 = blockIdx.x * 128, col0 = blockIdx.y * 128;
    int wid = tid >> 6, lane = tid & 63;
    int wm = wid >> 1, wn = wid & 1;
    int g = lane >> 4, c = lane & 15;
    f32x4 acc[4][4];
#pragma unroll
    for (int i = 0; i < 4; ++i)
#pragma unroll
        for (int j = 0; j < 4; ++j) acc[i][j] = (f32x4){0.f, 0.f, 0.f, 0.f};

    for (int k0 = 0; k0 < 256; k0 += 32) {
#pragma unroll
        for (int it = 0; it < 2; ++it) {
            int idx = tid + it * 256;
            int r = idx >> 2, ch = idx & 3;
            *(bf16x8*)&As[idx * 8] =
                *(const bf16x8*)&A[(size_t)(row0 + r) * 256 + k0 + ch * 8];
            *(bf16x8*)&Bs[idx * 8] =
                *(const bf16x8*)&W[(size_t)(col0 + r) * 256 + k0 + ch * 8];
        }
        __syncthreads();
        bf16x8 af[4], bfr[4];
#pragma unroll
        for (int mf = 0; mf < 4; ++mf)
            af[mf] = *(const bf16x8*)&As[(wm * 64 + mf * 16 + c) * 32 + g * 8];
#pragma unroll
        for (int nf = 0; nf < 4; ++nf)
            bfr[nf] = *(const bf16x8*)&Bs[(wn * 64 + nf * 16 + c) * 32 + g * 8];
#pragma unroll
        for (int mf = 0; mf < 4; ++mf)
#pragma unroll
            for (int nf = 0; nf < 4; ++nf)
                acc[mf][nf] = __builtin_amdgcn_mfma_f32_16x16x32_bf16(
                    af[mf], bfr[nf], acc[mf][nf], 0, 0, 0);
        __syncthreads();
    }
    short* Cb = (short*)Cout;
    float* Cf = (float*)Cout;
#pragma unroll
    for (int nf = 0; nf < 4; ++nf) {
        int col = col0 + wn * 64 + nf * 16 + c;
        float bz = bias[col];
#pragma unroll
        for (int mf = 0; mf < 4; ++mf)
#pragma unroll
            for (int r = 0; r < 4; ++r) {
                int row = row0 + wm * 64 + mf * 16 + g * 4 + r;
                float v = acc[mf][nf][r] + bz;
                if (OUT_BF) Cb[(size_t)row * 256 + col] = f2bf(v);
                else        Cf[(size_t)row * 256 + col] = v;
            }
    }
}

// ---------------- K4: fused MFMA attention per (b,n,h) ----------------
// 8 waves (512 thr); wave owns 64 t rows (4 t-frags of 16). No-max softmax.
// S^T = mfma_16x16x32(K_frag, Q_frag): lane holds P^T in the A-fragment
// layout of mfma_16x16x16 -> softmax fully in-register.
__global__ __launch_bounds__(512, 4) void attn_kernel(
    const short* __restrict__ Q, const short* __restrict__ K,
    const short* __restrict__ V, const int* __restrict__ mask,
    short* __restrict__ ctx) {
    __shared__ __align__(16) short K_lds[512 * 32];   // unpadded 64B rows
    __shared__ __align__(16) short V_lds[512 * 32];
    __shared__ __align__(16) float mb_lds[512];
    int tid = threadIdx.x;
    int bx = blockIdx.x;
    int h = bx & 7, bn = bx >> 3, b = bn >> 3;
    size_t kvbase = (size_t)bn * 512 * 256 + h * 32;
    const short* kg = K + kvbase;
    const short* vg = V + kvbase;
#pragma unroll
    for (int it = 0; it < 4; ++it) {
        int idx = tid + it * 512;
        int l = idx >> 2, ch = idx & 3;
        *(bf16x8*)&K_lds[idx * 8] = *(const bf16x8*)&kg[(size_t)l * 256 + ch * 8];
        *(bf16x8*)&V_lds[idx * 8] = *(const bf16x8*)&vg[(size_t)l * 256 + ch * 8];
    }
    mb_lds[tid] = mask[bn * 512 + tid] ? 0.f : -1e9f;
    __syncthreads();

    int wid = tid >> 6, lane = tid & 63;
    int g = lane >> 4, c = lane & 15;
    int t0 = wid * 64;
    const short* qg = Q + ((size_t)b * 512 + t0 + c) * 256 + h * 32 + g * 8;
    bf16x8 qf[4];
#pragma unroll
    for (int tf = 0; tf < 4; ++tf)
        qf[tf] = *(const bf16x8*)&qg[(size_t)tf * 16 * 256];

    f32x4 ctxa[4][2];
    f32x4 rsv[4];
#pragma unroll
    for (int tf = 0; tf < 4; ++tf) {
        ctxa[tf][0] = (f32x4){0.f, 0.f, 0.f, 0.f};
        ctxa[tf][1] = (f32x4){0.f, 0.f, 0.f, 0.f};
        rsv[tf] = (f32x4){0.f, 0.f, 0.f, 0.f};
    }
    const float SCALE2 = 0.25503482f;   // (1/sqrt(32)) * log2(e)

    for (int l0 = 0; l0 < 512; l0 += 16) {
        bf16x8 ak = *(const bf16x8*)&K_lds[(l0 + c) * 32 + g * 8];
        f32x4 mbv = *(const f32x4*)&mb_lds[l0 + g * 4];
        bf16x4 vb[2];
#pragma unroll
        for (int df = 0; df < 2; ++df)
#pragma unroll
            for (int j = 0; j < 4; ++j)
                vb[df][j] = V_lds[(l0 + g * 4 + j) * 32 + df * 16 + c];
#pragma unroll
        for (int tf = 0; tf < 4; ++tf) {
            f32x4 s = __builtin_amdgcn_mfma_f32_16x16x32_bf16(
                ak, qf[tf], (f32x4){0.f, 0.f, 0.f, 0.f}, 0, 0, 0);
            f32x4 e = s * SCALE2 + mbv;
            float p0 = exp2f(e[0]);
            float p1 = exp2f(e[1]);
            float p2 = exp2f(e[2]);
            float p3 = exp2f(e[3]);
            rsv[tf] += (f32x4){p0, p1, p2, p3};
            bf16x4 pa;
            pa[0] = f2bf(p0); pa[1] = f2bf(p1);
            pa[2] = f2bf(p2); pa[3] = f2bf(p3);
            ctxa[tf][0] = mfma16(pa, vb[0], ctxa[tf][0]);
            ctxa[tf][1] = mfma16(pa, vb[1], ctxa[tf][1]);
        }
    }
#ifndef HAVE_MFMA16
    asm volatile("s_nop 7\ns_nop 7");
#endif
    // rowsum reduce across the 4 l-groups; normalize ctx
#pragma unroll
    for (int tf = 0; tf < 4; ++tf) {
        float r = (rsv[tf][0] + rsv[tf][1]) + (rsv[tf][2] + rsv[tf][3]);
        r += __shfl_xor(r, 16);
        r += __shfl_xor(r, 32);
        float inv = 1.f / r;   // rowsum for t-row = c, replicated over groups
#pragma unroll
        for (int rr = 0; rr < 4; ++rr) {
            float invr = __shfl(inv, (lane & 48) | (g * 4 + rr));
            ctxa[tf][0][rr] *= invr;
            ctxa[tf][1][rr] *= invr;
        }
    }
    __syncthreads();   // all waves done reading K_lds; reuse as ctx staging
#pragma unroll
    for (int tf = 0; tf < 4; ++tf)
#pragma unroll
        for (int df = 0; df < 2; ++df)
#pragma unroll
            for (int rr = 0; rr < 4; ++rr)
                K_lds[(t0 + tf * 16 + g * 4 + rr) * 32 + df * 16 + c] =
                    f2bf(ctxa[tf][df][rr]);
    __syncthreads();
    short* cg = ctx + kvbase;
#pragma unroll
    for (int it = 0; it < 4; ++it) {
        int idx = tid + it * 512;
        int l = idx >> 2, ch = idx & 3;
        *(bf16x8*)&cg[(size_t)l * 256 + ch * 8] = *(const bf16x8*)&K_lds[idx * 8];
    }
}

// ---------------- K5: out = mean_n (x_pe + attn) * edge ----------------
__global__ __launch_bounds__(256) void final_kernel(
    const float* __restrict__ xpe, const float* __restrict__ attn,
    const float* __restrict__ nbr_edge, const float* __restrict__ Wedge,
    const float* __restrict__ bedge, float* __restrict__ out) {
    int row = blockIdx.x;
    int tid = threadIdx.x;
    int b = row >> 9, t = row & 511;
    float xp = xpe[(size_t)row * 256 + tid];
    float we[8];
#pragma unroll
    for (int cc = 0; cc < 8; ++cc) we[cc] = Wedge[tid * 8 + cc];
    float be = bedge[tid];
    float acc = 0.f;
#pragma unroll
    for (int n = 0; n < 8; ++n) {
        size_t bn = (size_t)(b * 8 + n);
        float av = attn[(bn * 512 + t) * 256 + tid];
        float eg = be;
#pragma unroll
        for (int cc = 0; cc < 8; ++cc)
            eg = fmaf(nbr_edge[(bn * 8 + cc) * 512 + t], we[cc], eg);
        acc = fmaf(xp + av, eg, acc);
    }
    out[(size_t)row * 256 + tid] = acc * 0.125f;
}

extern "C" void kernel_launch(void* const* d_in, const int* in_sizes, int n_in,
                              void* d_out, int out_size, void* d_ws, size_t ws_size,
                              hipStream_t stream) {
    const float* x        = (const float*)d_in[0];
    const float* nbr_ts   = (const float*)d_in[1];
    const float* nbr_aux  = (const float*)d_in[2];
    const float* nbr_edge = (const float*)d_in[3];
    const int*   mask     = (const int*)d_in[4];
    const float* Wts  = (const float*)d_in[5];
    const float* bts  = (const float*)d_in[6];
    const float* Waux = (const float*)d_in[7];
    const float* baux = (const float*)d_in[8];
    const float* Wedge= (const float*)d_in[9];
    const float* bedge= (const float*)d_in[10];
    const float* ln_a = (const float*)d_in[11];
    const float* ln_b = (const float*)d_in[12];
    const float* Wq = (const float*)d_in[13];
    const float* bq = (const float*)d_in[14];
    const float* Wk = (const float*)d_in[15];
    const float* bk = (const float*)d_in[16];
    const float* Wv = (const float*)d_in[17];
    const float* bv = (const float*)d_in[18];
    const float* Wo = (const float*)d_in[19];
    const float* bo = (const float*)d_in[20];
    float* out = (float*)d_out;

    char* W = (char*)d_ws;
    float* pe_f   = (float*)(W);                  // 512 KB
    float* xpe_f  = (float*)(W + 524288);         // 4 MB
    float* attn_f = (float*)(W + 4718592);        // 32 MB (also hosts W2/bias2 early)
    short* qin_bf = (short*)(W + 38273024);       // 2 MB
    short* q_bf   = (short*)(W + 40370176);       // 2 MB
    short* kv_bf  = (short*)(W + 42467328);       // 16 MB
    short* k_bf   = (short*)(W + 59244544);       // 16 MB
    short* v_bf   = (short*)(W + 76021760);       // 16 MB
    short* ctx_bf = (short*)(W + 92798976);       // 16 MB
    short* w_bf   = (short*)(W + 109576192);      // 512 KB
    short* wq_bf = w_bf;
    short* wk_bf = w_bf + 65536;
    short* wv_bf = w_bf + 131072;
    short* wo_bf = w_bf + 196608;
    // W2/bias2 live inside the attn_f region (attn_f is only written later
    // by the Wo-GEMM, after kv_gemm has consumed W2).
    short* W2_bf   = (short*)(W + 4718592);       // 48 KB
    float* bias2_f = (float*)(W + 4718592 + 49152);

    wconv_kernel<<<256, 256, 0, stream>>>(Wq, Wk, Wv, Wo, w_bf);
    prep2_kernel<<<96, 256, 0, stream>>>(Wts, Waux, bts, baux, W2_bf, bias2_f);
    pe_kernel<<<512, 256, 0, stream>>>(pe_f);
    kv_gemm<<<dim3(64, 4), 512, 0, stream>>>(nbr_ts, nbr_aux, W2_bf, bias2_f,
                                             pe_f, kv_bf);
    ln_kernel<<<4096, 256, 0, stream>>>(x, pe_f, ln_a, ln_b, xpe_f, qin_bf);
    gemm_bf16<1><<<dim3(32, 2),  256, 0, stream>>>(qin_bf, wq_bf, bq, q_bf);
    gemm_bf16<1><<<dim3(256, 2), 256, 0, stream>>>(kv_bf, wk_bf, bk, k_bf);
    gemm_bf16<1><<<dim3(256, 2), 256, 0, stream>>>(kv_bf, wv_bf, bv, v_bf);
    attn_kernel<<<512, 512, 0, stream>>>(q_bf, k_bf, v_bf, mask, ctx_bf);
    gemm_bf16<0><<<dim3(256, 2), 256, 0, stream>>>(ctx_bf, wo_bf, bo, attn_f);
    final_kernel<<<4096, 256, 0, stream>>>(xpe_f, attn_f, nbr_edge, Wedge, bedge, out);
}

// Round 4
// 131.589 us; speedup vs baseline: 3.0613x; 1.1815x over previous
//
#include <hip/hip_runtime.h>
#include <hip/hip_bf16.h>
#include <math.h>

// Dims: B=8, N=8, T=512, L=512, d=256, H=8, dk=32
typedef __attribute__((ext_vector_type(8))) short bf16x8;
typedef __attribute__((ext_vector_type(4))) short bf16x4;
typedef __attribute__((ext_vector_type(4))) float f32x4;

__device__ __forceinline__ short f2bf(float f) {
    return (short)__builtin_bit_cast(unsigned short, __float2bfloat16(f));
}
__device__ __forceinline__ float bf2f(short s) {
    return __builtin_bit_cast(float, ((unsigned)(unsigned short)s) << 16);
}

#if defined(__has_builtin)
#if __has_builtin(__builtin_amdgcn_mfma_f32_16x16x16bf16_1k)
#define HAVE_MFMA16 1
#endif
#endif

__device__ __forceinline__ f32x4 mfma16(bf16x4 a, bf16x4 b, f32x4 c) {
#ifdef HAVE_MFMA16
    return __builtin_amdgcn_mfma_f32_16x16x16bf16_1k(a, b, c, 0, 0, 0);
#else
    f32x4 d;
    asm volatile("v_mfma_f32_16x16x16_bf16 %0, %1, %2, %3"
                 : "=v"(d) : "v"(a), "v"(b), "v"(c));
    return d;
#endif
}

// ---------------- K0: PE table (512 x 256) f32 ----------------
__global__ void pe_kernel(float* __restrict__ pe) {
    int t = blockIdx.x, dd = threadIdx.x;
    int i = dd >> 1;
    float div = expf((float)(2 * i) * (-9.210340371976184f / 256.0f));
    float ang = (float)t * div;
    pe[t * 256 + dd] = (dd & 1) ? cosf(ang) : sinf(ang);
}

// ---------------- weights -> bf16 ----------------
__global__ __launch_bounds__(256) void wconv_kernel(
    const float* __restrict__ Wq, const float* __restrict__ Wk,
    const float* __restrict__ Wv, const float* __restrict__ Wo,
    short* __restrict__ out) {
    int i = blockIdx.x * 256 + threadIdx.x;   // 65536 per matrix
    out[i]          = f2bf(Wq[i]);
    out[65536 + i]  = f2bf(Wk[i]);
    out[131072 + i] = f2bf(Wv[i]);
    out[196608 + i] = f2bf(Wo[i]);
}

// ---------------- prep2: W2 [256][96] bf16, bias2, bkv ----------------
__global__ __launch_bounds__(256) void prep2_kernel(
    const float* __restrict__ Wts, const float* __restrict__ Waux,
    const float* __restrict__ bts, const float* __restrict__ baux,
    const float* __restrict__ bk, const float* __restrict__ bv,
    short* __restrict__ W2, float* __restrict__ bias2,
    float* __restrict__ bkv) {
    int idx = blockIdx.x * 256 + threadIdx.x;   // 96*256 = 24576
    int e = idx / 96, ch = idx - e * 96;
    float v = 0.f;
    if (ch < 64) { if (e < 192) v = Wts[e * 64 + ch]; }
    else if (ch < 80) { if (e >= 192) v = Waux[(e - 192) * 16 + (ch - 64)]; }
    W2[idx] = f2bf(v);
    if (idx < 256) bias2[idx] = idx < 192 ? bts[idx] : baux[idx - 192];
    if (idx < 512) bkv[idx] = idx < 256 ? bk[idx] : bv[idx - 256];
}

// ---------------- valid-index compaction per (b,n) ----------------
__global__ __launch_bounds__(512) void vidx_kernel(
    const int* __restrict__ mask, int* __restrict__ vidx, int* __restrict__ cnt) {
    int bn = blockIdx.x, tid = threadIdx.x;
    int lane = tid & 63, wid = tid >> 6;
    int m = mask[bn * 512 + tid] != 0;
    int v = m;
#pragma unroll
    for (int off = 1; off < 64; off <<= 1) {
        int t = __shfl_up(v, off);
        if (lane >= off) v += t;
    }
    __shared__ int wsum[8];
    if (lane == 63) wsum[wid] = v;
    __syncthreads();
    int base = 0;
#pragma unroll
    for (int w = 0; w < 8; ++w) base += (w < wid) ? wsum[w] : 0;
    if (m) vidx[bn * 512 + base + v - 1] = tid;
    if (tid == 511) cnt[bn] = base + v;
}

// ---------------- kv embed as MFMA GEMM over K=96 ----------------
__global__ __launch_bounds__(512, 2) void kv_gemm(
    const float* __restrict__ nbr_ts, const float* __restrict__ nbr_aux,
    const short* __restrict__ W2, const float* __restrict__ bias2,
    const float* __restrict__ pe, short* __restrict__ kv) {
    __shared__ __align__(16) float S1[64 * 132];
    __shared__ __align__(16) float S2[16 * 132];
    __shared__ __align__(16) short A_lds[128 * 104];
    int tid = threadIdx.x;
    int bn = blockIdx.x, l0 = blockIdx.y * 128;
    const float* tsb = nbr_ts + (size_t)bn * 64 * 512;
    const float* axb = nbr_aux + (size_t)bn * 16 * 512;
#pragma unroll
    for (int it = 0; it < 4; ++it) {
        int idx = tid + it * 512;
        int cc = idx >> 5, lq = idx & 31;
        *(float4*)&S1[cc * 132 + lq * 4] =
            *(const float4*)&tsb[(size_t)cc * 512 + l0 + lq * 4];
    }
    {
        int cc = tid >> 5, lq = tid & 31;
        *(float4*)&S2[cc * 132 + lq * 4] =
            *(const float4*)&axb[(size_t)cc * 512 + l0 + lq * 4];
    }
    __syncthreads();
#pragma unroll
    for (int p = 0; p < 3; ++p) {
        int tk = tid + p * 512;
        int l = tk & 127, chunk = tk >> 7;
        short v8[8];
        if (chunk < 8) {
#pragma unroll
            for (int i = 0; i < 8; ++i) v8[i] = f2bf(S1[(chunk * 8 + i) * 132 + l]);
        } else if (chunk < 10) {
#pragma unroll
            for (int i = 0; i < 8; ++i) v8[i] = f2bf(S2[((chunk - 8) * 8 + i) * 132 + l]);
        } else {
#pragma unroll
            for (int i = 0; i < 8; ++i) v8[i] = 0;
        }
        *(bf16x8*)&A_lds[l * 104 + chunk * 8] = *(bf16x8*)v8;
    }
    __syncthreads();
    int wid = tid >> 6, lane = tid & 63;
    int g = lane >> 4, c = lane & 15;
    int lm = wid >> 2, le = wid & 3;
    bf16x8 wf[4][3];
#pragma unroll
    for (int nf = 0; nf < 4; ++nf)
#pragma unroll
        for (int ks = 0; ks < 3; ++ks)
            wf[nf][ks] = *(const bf16x8*)&W2[(size_t)(le * 64 + nf * 16 + c) * 96 +
                                             ks * 32 + g * 8];
    f32x4 acc[4][4];
#pragma unroll
    for (int i = 0; i < 4; ++i)
#pragma unroll
        for (int j = 0; j < 4; ++j) acc[i][j] = (f32x4){0.f, 0.f, 0.f, 0.f};
#pragma unroll
    for (int ks = 0; ks < 3; ++ks) {
#pragma unroll
        for (int mf = 0; mf < 4; ++mf) {
            bf16x8 af = *(const bf16x8*)&A_lds[(lm * 64 + mf * 16 + c) * 104 +
                                               ks * 32 + g * 8];
#pragma unroll
            for (int nf = 0; nf < 4; ++nf)
                acc[mf][nf] = __builtin_amdgcn_mfma_f32_16x16x32_bf16(
                    af, wf[nf][ks], acc[mf][nf], 0, 0, 0);
        }
    }
    short* kvb = kv + ((size_t)bn * 512 + l0) * 256;
#pragma unroll
    for (int nf = 0; nf < 4; ++nf) {
        int e = le * 64 + nf * 16 + c;
        float b2 = bias2[e];
#pragma unroll
        for (int mf = 0; mf < 4; ++mf) {
            int lr = lm * 64 + mf * 16 + g * 4;
#pragma unroll
            for (int r = 0; r < 4; ++r) {
                float v = acc[mf][nf][r] + b2 + pe[(size_t)(l0 + lr + r) * 256 + e];
                kvb[(size_t)(lr + r) * 256 + e] = f2bf(v);
            }
        }
    }
}

// ---------------- K2: x_pe + LayerNorm (ddof=1), bf16 qin ----------------
__global__ __launch_bounds__(256) void ln_kernel(
    const float* __restrict__ x, const float* __restrict__ pe,
    const float* __restrict__ ln_a, const float* __restrict__ ln_b,
    float* __restrict__ xpe, short* __restrict__ qin) {
    int row = blockIdx.x;
    int t = row & 511;
    int tid = threadIdx.x;
    float v = x[(size_t)row * 256 + tid] + pe[t * 256 + tid];
    xpe[(size_t)row * 256 + tid] = v;

    __shared__ float red[4];
    float s = v;
#pragma unroll
    for (int off = 32; off > 0; off >>= 1) s += __shfl_xor(s, off);
    if ((tid & 63) == 0) red[tid >> 6] = s;
    __syncthreads();
    float mu = (red[0] + red[1] + red[2] + red[3]) * (1.0f / 256.0f);
    float dv = v - mu;
    float s2 = dv * dv;
#pragma unroll
    for (int off = 32; off > 0; off >>= 1) s2 += __shfl_xor(s2, off);
    __syncthreads();
    if ((tid & 63) == 0) red[tid >> 6] = s2;
    __syncthreads();
    float var = (red[0] + red[1] + red[2] + red[3]) * (1.0f / 255.0f);
    float sd = sqrtf(var);
    qin[(size_t)row * 256 + tid] = f2bf(ln_a[tid] * dv / (sd + 1e-6f) + ln_b[tid]);
}

// ---------------- bf16 MFMA GEMM: C[M x (2N?)] = A[M x 256] @ W^T + bias ----------------
// tile 128x128, 4 waves (2x2), wave 64x64 = 4x4 frags, K-step 32. LDC = C row stride.
template <int OUT_BF, int LDC>
__global__ __launch_bounds__(256) void gemm_bf16(
    const short* __restrict__ A, const short* __restrict__ W,
    const float* __restrict__ bias, void* __restrict__ Cout) {
    __shared__ __align__(16) short As[128 * 32];
    __shared__ __align__(16) short Bs[128 * 32];
    int tid = threadIdx.x;
    int row0 = blockIdx.x * 128, col0 = blockIdx.y * 128;
    int wid = tid >> 6, lane = tid & 63;
    int wm = wid >> 1, wn = wid & 1;
    int g = lane >> 4, c = lane & 15;
    f32x4 acc[4][4];
#pragma unroll
    for (int i = 0; i < 4; ++i)
#pragma unroll
        for (int j = 0; j < 4; ++j) acc[i][j] = (f32x4){0.f, 0.f, 0.f, 0.f};

    for (int k0 = 0; k0 < 256; k0 += 32) {
#pragma unroll
        for (int it = 0; it < 2; ++it) {
            int idx = tid + it * 256;
            int r = idx >> 2, ch = idx & 3;
            *(bf16x8*)&As[idx * 8] =
                *(const bf16x8*)&A[(size_t)(row0 + r) * 256 + k0 + ch * 8];
            *(bf16x8*)&Bs[idx * 8] =
                *(const bf16x8*)&W[(size_t)(col0 + r) * 256 + k0 + ch * 8];
        }
        __syncthreads();
        bf16x8 af[4], bfr[4];
#pragma unroll
        for (int mf = 0; mf < 4; ++mf)
            af[mf] = *(const bf16x8*)&As[(wm * 64 + mf * 16 + c) * 32 + g * 8];
#pragma unroll
        for (int nf = 0; nf < 4; ++nf)
            bfr[nf] = *(const bf16x8*)&Bs[(wn * 64 + nf * 16 + c) * 32 + g * 8];
#pragma unroll
        for (int mf = 0; mf < 4; ++mf)
#pragma unroll
            for (int nf = 0; nf < 4; ++nf)
                acc[mf][nf] = __builtin_amdgcn_mfma_f32_16x16x32_bf16(
                    af[mf], bfr[nf], acc[mf][nf], 0, 0, 0);
        __syncthreads();
    }
    short* Cb = (short*)Cout;
    float* Cf = (float*)Cout;
#pragma unroll
    for (int nf = 0; nf < 4; ++nf) {
        int col = col0 + wn * 64 + nf * 16 + c;
        float bz = bias[col];
#pragma unroll
        for (int mf = 0; mf < 4; ++mf)
#pragma unroll
            for (int r = 0; r < 4; ++r) {
                int row = row0 + wm * 64 + mf * 16 + g * 4 + r;
                float v = acc[mf][nf][r] + bz;
                if (OUT_BF) Cb[(size_t)row * LDC + col] = f2bf(v);
                else        Cf[(size_t)row * LDC + col] = v;
            }
    }
}

// ---------------- K4: fused MFMA attention per (b,n,h), mask-compacted ----------------
// 8 waves (512 thr); wave owns 64 t rows (4 t-frags of 16). No-max softmax.
// K/V gathered to valid l's only; V stored transposed in LDS for b64 frag reads.
__global__ __launch_bounds__(512, 2) void attn_kernel(
    const short* __restrict__ Q, const short* __restrict__ KV2,
    const int* __restrict__ vidx, const int* __restrict__ cnt,
    short* __restrict__ ctx) {
    __shared__ __align__(16) short K_lds[512 * 40];    // [i][40] pad rows
    __shared__ __align__(16) short Vt_lds[32 * 524];   // [d][524] transposed
    __shared__ __align__(16) float mb_lds[512];
    int tid = threadIdx.x;
    int bx = blockIdx.x;
    int h = bx & 7, bn = bx >> 3, b = bn >> 3;
    int nv = cnt[bn];
    int nvp = (nv + 15) & ~15;
    const short* kg = KV2 + (size_t)bn * 512 * 512 + h * 32;
    const short* vg = kg + 256;
    const int* vix = vidx + bn * 512;
#pragma unroll
    for (int it = 0; it < 4; ++it) {
        int idx = tid + it * 512;
        int i = idx >> 2, ch = idx & 3;
        if (i < nvp) {
            bf16x8 kval = (bf16x8){0, 0, 0, 0, 0, 0, 0, 0};
            bf16x8 vval = (bf16x8){0, 0, 0, 0, 0, 0, 0, 0};
            if (i < nv) {
                size_t ro = (size_t)vix[i] * 512;
                kval = *(const bf16x8*)&kg[ro + ch * 8];
                vval = *(const bf16x8*)&vg[ro + ch * 8];
            }
            *(bf16x8*)&K_lds[i * 40 + ch * 8] = kval;
#pragma unroll
            for (int k = 0; k < 8; ++k)
                Vt_lds[(ch * 8 + k) * 524 + i] = vval[k];
        }
    }
    mb_lds[tid] = (tid < nv) ? 0.f : -1e9f;
    __syncthreads();

    int wid = tid >> 6, lane = tid & 63;
    int g = lane >> 4, c = lane & 15;
    int t0 = wid * 64;
    const short* qg = Q + ((size_t)b * 512 + t0 + c) * 256 + h * 32 + g * 8;
    bf16x8 qf[4];
#pragma unroll
    for (int tf = 0; tf < 4; ++tf)
        qf[tf] = *(const bf16x8*)&qg[(size_t)tf * 16 * 256];

    f32x4 ctxa[4][2];
    f32x4 rsv[4];
#pragma unroll
    for (int tf = 0; tf < 4; ++tf) {
        ctxa[tf][0] = (f32x4){0.f, 0.f, 0.f, 0.f};
        ctxa[tf][1] = (f32x4){0.f, 0.f, 0.f, 0.f};
        rsv[tf] = (f32x4){0.f, 0.f, 0.f, 0.f};
    }
    const float SCALE2 = 0.25503482f;   // (1/sqrt(32)) * log2(e)

    for (int l0 = 0; l0 < nvp; l0 += 16) {
        bf16x8 ak = *(const bf16x8*)&K_lds[(l0 + c) * 40 + g * 8];
        f32x4 mbv = *(const f32x4*)&mb_lds[l0 + g * 4];
        bf16x4 vb[2];
        vb[0] = *(const bf16x4*)&Vt_lds[c * 524 + l0 + g * 4];
        vb[1] = *(const bf16x4*)&Vt_lds[(16 + c) * 524 + l0 + g * 4];
#pragma unroll
        for (int tf = 0; tf < 4; ++tf) {
            f32x4 s = __builtin_amdgcn_mfma_f32_16x16x32_bf16(
                ak, qf[tf], (f32x4){0.f, 0.f, 0.f, 0.f}, 0, 0, 0);
            f32x4 e = s * SCALE2 + mbv;
            float p0 = exp2f(e[0]);
            float p1 = exp2f(e[1]);
            float p2 = exp2f(e[2]);
            float p3 = exp2f(e[3]);
            rsv[tf] += (f32x4){p0, p1, p2, p3};
            bf16x4 pa;
            pa[0] = f2bf(p0); pa[1] = f2bf(p1);
            pa[2] = f2bf(p2); pa[3] = f2bf(p3);
            ctxa[tf][0] = mfma16(pa, vb[0], ctxa[tf][0]);
            ctxa[tf][1] = mfma16(pa, vb[1], ctxa[tf][1]);
        }
    }
#ifndef HAVE_MFMA16
    asm volatile("s_nop 7\ns_nop 7");
#endif
#pragma unroll
    for (int tf = 0; tf < 4; ++tf) {
        float r = (rsv[tf][0] + rsv[tf][1]) + (rsv[tf][2] + rsv[tf][3]);
        r += __shfl_xor(r, 16);
        r += __shfl_xor(r, 32);
        float inv = 1.f / r;   // rowsum for t-row = c, replicated over groups
#pragma unroll
        for (int rr = 0; rr < 4; ++rr) {
            float invr = __shfl(inv, (lane & 48) | (g * 4 + rr));
            ctxa[tf][0][rr] *= invr;
            ctxa[tf][1][rr] *= invr;
        }
    }
    __syncthreads();   // all waves done with K_lds/Vt_lds; reuse K_lds as ctx staging
#pragma unroll
    for (int tf = 0; tf < 4; ++tf)
#pragma unroll
        for (int df = 0; df < 2; ++df)
#pragma unroll
            for (int rr = 0; rr < 4; ++rr)
                K_lds[(t0 + tf * 16 + g * 4 + rr) * 40 + df * 16 + c] =
                    f2bf(ctxa[tf][df][rr]);
    __syncthreads();
    short* cg = ctx + (size_t)bn * 512 * 256 + h * 32;
#pragma unroll
    for (int it = 0; it < 4; ++it) {
        int idx = tid + it * 512;
        int l = idx >> 2, ch = idx & 3;
        *(bf16x8*)&cg[(size_t)l * 256 + ch * 8] =
            *(const bf16x8*)&K_lds[l * 40 + ch * 8];
    }
}

// ---------------- K5: out = mean_n (x_pe + attn) * edge ----------------
__global__ __launch_bounds__(256) void final_kernel(
    const float* __restrict__ xpe, const short* __restrict__ attn,
    const float* __restrict__ nbr_edge, const float* __restrict__ Wedge,
    const float* __restrict__ bedge, float* __restrict__ out) {
    int row = blockIdx.x;
    int tid = threadIdx.x;
    int b = row >> 9, t = row & 511;
    float xp = xpe[(size_t)row * 256 + tid];
    float we[8];
#pragma unroll
    for (int cc = 0; cc < 8; ++cc) we[cc] = Wedge[tid * 8 + cc];
    float be = bedge[tid];
    float acc = 0.f;
#pragma unroll
    for (int n = 0; n < 8; ++n) {
        size_t bn = (size_t)(b * 8 + n);
        float av = bf2f(attn[(bn * 512 + t) * 256 + tid]);
        float eg = be;
#pragma unroll
        for (int cc = 0; cc < 8; ++cc)
            eg = fmaf(nbr_edge[(bn * 8 + cc) * 512 + t], we[cc], eg);
        acc = fmaf(xp + av, eg, acc);
    }
    out[(size_t)row * 256 + tid] = acc * 0.125f;
}

extern "C" void kernel_launch(void* const* d_in, const int* in_sizes, int n_in,
                              void* d_out, int out_size, void* d_ws, size_t ws_size,
                              hipStream_t stream) {
    const float* x        = (const float*)d_in[0];
    const float* nbr_ts   = (const float*)d_in[1];
    const float* nbr_aux  = (const float*)d_in[2];
    const float* nbr_edge = (const float*)d_in[3];
    const int*   mask     = (const int*)d_in[4];
    const float* Wts  = (const float*)d_in[5];
    const float* bts  = (const float*)d_in[6];
    const float* Waux = (const float*)d_in[7];
    const float* baux = (const float*)d_in[8];
    const float* Wedge= (const float*)d_in[9];
    const float* bedge= (const float*)d_in[10];
    const float* ln_a = (const float*)d_in[11];
    const float* ln_b = (const float*)d_in[12];
    const float* Wq = (const float*)d_in[13];
    const float* bq = (const float*)d_in[14];
    const float* Wk = (const float*)d_in[15];
    const float* bk = (const float*)d_in[16];
    const float* Wv = (const float*)d_in[17];
    const float* bv = (const float*)d_in[18];
    const float* Wo = (const float*)d_in[19];
    const float* bo = (const float*)d_in[20];
    float* out = (float*)d_out;

    char* W = (char*)d_ws;
    float* pe_f    = (float*)(W);                 // 512 KB
    float* xpe_f   = (float*)(W + 524288);        // 4 MB
    short* qin_bf  = (short*)(W + 4718592);       // 2 MB
    short* q_bf    = (short*)(W + 6815744);       // 2 MB
    short* kv_bf   = (short*)(W + 8912896);       // 16 MB
    short* kv2_bf  = (short*)(W + 25690112);      // 32 MB  (K|V fused, LDC 512)
    short* ctx_bf  = (short*)(W + 59244544);      // 16 MB
    short* attn_bf = (short*)(W + 76021760);      // 16 MB
    short* w_bf    = (short*)(W + 92798976);      // 512 KB
    short* W2_bf   = (short*)(W + 93323264);      // 48 KB
    float* bias2_f = (float*)(W + 93372416);      // 1 KB
    float* bkv_f   = (float*)(W + 93373440);      // 2 KB
    int*   vidx    = (int*)  (W + 93375488);      // 128 KB
    int*   cnt     = (int*)  (W + 93506560);      // 256 B
    short* wq_bf = w_bf;
    short* wk_bf = w_bf + 65536;   // wk,wv contiguous => one [512][256] matrix
    short* wo_bf = w_bf + 196608;

    wconv_kernel<<<256, 256, 0, stream>>>(Wq, Wk, Wv, Wo, w_bf);
    prep2_kernel<<<96, 256, 0, stream>>>(Wts, Waux, bts, baux, bk, bv,
                                         W2_bf, bias2_f, bkv_f);
    pe_kernel<<<512, 256, 0, stream>>>(pe_f);
    vidx_kernel<<<64, 512, 0, stream>>>(mask, vidx, cnt);
    kv_gemm<<<dim3(64, 4), 512, 0, stream>>>(nbr_ts, nbr_aux, W2_bf, bias2_f,
                                             pe_f, kv_bf);
    ln_kernel<<<4096, 256, 0, stream>>>(x, pe_f, ln_a, ln_b, xpe_f, qin_bf);
    gemm_bf16<1, 256><<<dim3(32, 2),  256, 0, stream>>>(qin_bf, wq_bf, bq, q_bf);
    gemm_bf16<1, 512><<<dim3(256, 4), 256, 0, stream>>>(kv_bf, wk_bf, bkv_f, kv2_bf);
    attn_kernel<<<512, 512, 0, stream>>>(q_bf, kv2_bf, vidx, cnt, ctx_bf);
    gemm_bf16<1, 256><<<dim3(256, 2), 256, 0, stream>>>(ctx_bf, wo_bf, bo, attn_bf);
    final_kernel<<<4096, 256, 0, stream>>>(xpe_f, attn_bf, nbr_edge, Wedge,
                                           bedge, out);
}

// Round 5
// 127.666 us; speedup vs baseline: 3.1554x; 1.0307x over previous
//
#include <hip/hip_runtime.h>
#include <hip/hip_bf16.h>
#include <math.h>

// Dims: B=8, N=8, T=512, L=512, d=256, H=8, dk=32
typedef __attribute__((ext_vector_type(8))) short bf16x8;
typedef __attribute__((ext_vector_type(4))) short bf16x4;
typedef __attribute__((ext_vector_type(4))) float f32x4;

__device__ __forceinline__ short f2bf(float f) {
    return (short)__builtin_bit_cast(unsigned short, __float2bfloat16(f));
}
__device__ __forceinline__ float bf2f(short s) {
    return __builtin_bit_cast(float, ((unsigned)(unsigned short)s) << 16);
}

#if defined(__has_builtin)
#if __has_builtin(__builtin_amdgcn_mfma_f32_16x16x16bf16_1k)
#define HAVE_MFMA16 1
#endif
#endif

__device__ __forceinline__ f32x4 mfma16(bf16x4 a, bf16x4 b, f32x4 c) {
#ifdef HAVE_MFMA16
    return __builtin_amdgcn_mfma_f32_16x16x16bf16_1k(a, b, c, 0, 0, 0);
#else
    f32x4 d;
    asm volatile("v_mfma_f32_16x16x16_bf16 %0, %1, %2, %3"
                 : "=v"(d) : "v"(a), "v"(b), "v"(c));
    return d;
#endif
}

#define SCALE2 0.25503482403f   // (1/sqrt(32)) * log2(e)

// ---------------- prep: weights->bf16, W2/bias2/bkv, PE table ----------------
__global__ __launch_bounds__(256) void prep_kernel(
    const float* __restrict__ Wq, const float* __restrict__ Wk,
    const float* __restrict__ Wv, const float* __restrict__ Wo,
    const float* __restrict__ Wts, const float* __restrict__ Waux,
    const float* __restrict__ bts, const float* __restrict__ baux,
    const float* __restrict__ bk, const float* __restrict__ bv,
    short* __restrict__ wout, short* __restrict__ W2,
    float* __restrict__ bias2, float* __restrict__ bkv,
    float* __restrict__ pe) {
    int bid = blockIdx.x, tid = threadIdx.x;
    if (bid < 256) {
        int i = bid * 256 + tid;
        wout[i]          = f2bf(Wq[i]);
        wout[65536 + i]  = f2bf(Wk[i]);
        wout[131072 + i] = f2bf(Wv[i]);
        wout[196608 + i] = f2bf(Wo[i]);
    } else if (bid < 352) {
        int idx = (bid - 256) * 256 + tid;   // 96*256 = 24576
        int e = idx / 96, ch = idx - e * 96;
        float v = 0.f;
        if (ch < 64) { if (e < 192) v = Wts[e * 64 + ch]; }
        else if (ch < 80) { if (e >= 192) v = Waux[(e - 192) * 16 + (ch - 64)]; }
        W2[idx] = f2bf(v);
        if (idx < 256) bias2[idx] = idx < 192 ? bts[idx] : baux[idx - 192];
        if (idx < 512) bkv[idx] = idx < 256 ? bk[idx] : bv[idx - 256];
    } else {
        int t = bid - 352, dd = tid;
        int i = dd >> 1;
        float div = expf((float)(2 * i) * (-9.210340371976184f / 256.0f));
        float ang = (float)t * div;
        pe[t * 256 + dd] = (dd & 1) ? cosf(ang) : sinf(ang);
    }
}

// ---------------- compaction: pos[l] (or -1) and cnt per (b,n) ----------------
__global__ __launch_bounds__(512) void pos_kernel(
    const int* __restrict__ mask, int* __restrict__ pos, int* __restrict__ cnt) {
    int bn = blockIdx.x, tid = threadIdx.x;
    int lane = tid & 63, wid = tid >> 6;
    int m = mask[bn * 512 + tid] != 0;
    int v = m;
#pragma unroll
    for (int off = 1; off < 64; off <<= 1) {
        int t = __shfl_up(v, off);
        if (lane >= off) v += t;
    }
    __shared__ int wsum[8];
    if (lane == 63) wsum[wid] = v;
    __syncthreads();
    int base = 0;
#pragma unroll
    for (int w = 0; w < 8; ++w) base += (w < wid) ? wsum[w] : 0;
    pos[bn * 512 + tid] = m ? (base + v - 1) : -1;
    if (tid == 511) cnt[bn] = base + v;
}

// ---------------- kv embed as MFMA GEMM over K=96, scatter to compacted rows ----------------
__global__ __launch_bounds__(512, 2) void kv_gemm(
    const float* __restrict__ nbr_ts, const float* __restrict__ nbr_aux,
    const short* __restrict__ W2, const float* __restrict__ bias2,
    const float* __restrict__ pe, const int* __restrict__ pos,
    short* __restrict__ kvc) {
    __shared__ __align__(16) float S1[64 * 132];
    __shared__ __align__(16) float S2[16 * 132];
    __shared__ __align__(16) short A_lds[128 * 104];
    int tid = threadIdx.x;
    int bn = blockIdx.x, l0 = blockIdx.y * 128;
    const float* tsb = nbr_ts + (size_t)bn * 64 * 512;
    const float* axb = nbr_aux + (size_t)bn * 16 * 512;
#pragma unroll
    for (int it = 0; it < 4; ++it) {
        int idx = tid + it * 512;
        int cc = idx >> 5, lq = idx & 31;
        *(float4*)&S1[cc * 132 + lq * 4] =
            *(const float4*)&tsb[(size_t)cc * 512 + l0 + lq * 4];
    }
    {
        int cc = tid >> 5, lq = tid & 31;
        *(float4*)&S2[cc * 132 + lq * 4] =
            *(const float4*)&axb[(size_t)cc * 512 + l0 + lq * 4];
    }
    __syncthreads();
#pragma unroll
    for (int p = 0; p < 3; ++p) {
        int tk = tid + p * 512;
        int l = tk & 127, chunk = tk >> 7;
        short v8[8];
        if (chunk < 8) {
#pragma unroll
            for (int i = 0; i < 8; ++i) v8[i] = f2bf(S1[(chunk * 8 + i) * 132 + l]);
        } else if (chunk < 10) {
#pragma unroll
            for (int i = 0; i < 8; ++i) v8[i] = f2bf(S2[((chunk - 8) * 8 + i) * 132 + l]);
        } else {
#pragma unroll
            for (int i = 0; i < 8; ++i) v8[i] = 0;
        }
        *(bf16x8*)&A_lds[l * 104 + chunk * 8] = *(bf16x8*)v8;
    }
    __syncthreads();
    int wid = tid >> 6, lane = tid & 63;
    int g = lane >> 4, c = lane & 15;
    int lm = wid >> 2, le = wid & 3;
    bf16x8 wf[4][3];
#pragma unroll
    for (int nf = 0; nf < 4; ++nf)
#pragma unroll
        for (int ks = 0; ks < 3; ++ks)
            wf[nf][ks] = *(const bf16x8*)&W2[(size_t)(le * 64 + nf * 16 + c) * 96 +
                                             ks * 32 + g * 8];
    f32x4 acc[4][4];
#pragma unroll
    for (int i = 0; i < 4; ++i)
#pragma unroll
        for (int j = 0; j < 4; ++j) acc[i][j] = (f32x4){0.f, 0.f, 0.f, 0.f};
#pragma unroll
    for (int ks = 0; ks < 3; ++ks) {
#pragma unroll
        for (int mf = 0; mf < 4; ++mf) {
            bf16x8 af = *(const bf16x8*)&A_lds[(lm * 64 + mf * 16 + c) * 104 +
                                               ks * 32 + g * 8];
#pragma unroll
            for (int nf = 0; nf < 4; ++nf)
                acc[mf][nf] = __builtin_amdgcn_mfma_f32_16x16x32_bf16(
                    af, wf[nf][ks], acc[mf][nf], 0, 0, 0);
        }
    }
    float b2c[4];
#pragma unroll
    for (int nf = 0; nf < 4; ++nf) b2c[nf] = bias2[le * 64 + nf * 16 + c];
    short* kvb = kvc + (size_t)bn * 512 * 256;
    const int* posb = pos + bn * 512 + l0;
#pragma unroll
    for (int mf = 0; mf < 4; ++mf) {
#pragma unroll
        for (int r = 0; r < 4; ++r) {
            int lr = lm * 64 + mf * 16 + g * 4 + r;
            int p = posb[lr];
            if (p >= 0) {
#pragma unroll
                for (int nf = 0; nf < 4; ++nf) {
                    int e = le * 64 + nf * 16 + c;
                    kvb[(size_t)p * 256 + e] =
                        f2bf(acc[mf][nf][r] + b2c[nf] +
                             pe[(size_t)(l0 + lr) * 256 + e]);
                }
            }
        }
    }
}

// ---------------- x_pe + LayerNorm (ddof=1), bf16 qin ----------------
__global__ __launch_bounds__(256) void ln_kernel(
    const float* __restrict__ x, const float* __restrict__ pe,
    const float* __restrict__ ln_a, const float* __restrict__ ln_b,
    float* __restrict__ xpe, short* __restrict__ qin) {
    int row = blockIdx.x;
    int t = row & 511;
    int tid = threadIdx.x;
    float v = x[(size_t)row * 256 + tid] + pe[t * 256 + tid];
    xpe[(size_t)row * 256 + tid] = v;

    __shared__ float red[4];
    float s = v;
#pragma unroll
    for (int off = 32; off > 0; off >>= 1) s += __shfl_xor(s, off);
    if ((tid & 63) == 0) red[tid >> 6] = s;
    __syncthreads();
    float mu = (red[0] + red[1] + red[2] + red[3]) * (1.0f / 256.0f);
    float dv = v - mu;
    float s2 = dv * dv;
#pragma unroll
    for (int off = 32; off > 0; off >>= 1) s2 += __shfl_xor(s2, off);
    __syncthreads();
    if ((tid & 63) == 0) red[tid >> 6] = s2;
    __syncthreads();
    float var = (red[0] + red[1] + red[2] + red[3]) * (1.0f / 255.0f);
    float sd = sqrtf(var);
    qin[(size_t)row * 256 + tid] = f2bf(ln_a[tid] * dv / (sd + 1e-6f) + ln_b[tid]);
}

// ---------------- bf16 MFMA GEMM: C[M x N] = escale*(A @ W^T + bias) ----------------
// tile 128x128, 4 waves (2x2), wave 64x64 = 4x4 frags, K-step 32.
// LDS rows padded to 40 shorts (80 B): frag reads 2-way (free).
template <int LDC>
__global__ __launch_bounds__(256) void gemm_bf16(
    const short* __restrict__ A, const short* __restrict__ W,
    const float* __restrict__ bias, short* __restrict__ Cout, float escale) {
    __shared__ __align__(16) short As[128 * 40];
    __shared__ __align__(16) short Bs[128 * 40];
    int tid = threadIdx.x;
    int row0 = blockIdx.x * 128, col0 = blockIdx.y * 128;
    int wid = tid >> 6, lane = tid & 63;
    int wm = wid >> 1, wn = wid & 1;
    int g = lane >> 4, c = lane & 15;
    f32x4 acc[4][4];
#pragma unroll
    for (int i = 0; i < 4; ++i)
#pragma unroll
        for (int j = 0; j < 4; ++j) acc[i][j] = (f32x4){0.f, 0.f, 0.f, 0.f};

    for (int k0 = 0; k0 < 256; k0 += 32) {
#pragma unroll
        for (int it = 0; it < 2; ++it) {
            int idx = tid + it * 256;
            int r = idx >> 2, ch = idx & 3;
            *(bf16x8*)&As[r * 40 + ch * 8] =
                *(const bf16x8*)&A[(size_t)(row0 + r) * 256 + k0 + ch * 8];
            *(bf16x8*)&Bs[r * 40 + ch * 8] =
                *(const bf16x8*)&W[(size_t)(col0 + r) * 256 + k0 + ch * 8];
        }
        __syncthreads();
        bf16x8 af[4], bfr[4];
#pragma unroll
        for (int mf = 0; mf < 4; ++mf)
            af[mf] = *(const bf16x8*)&As[(wm * 64 + mf * 16 + c) * 40 + g * 8];
#pragma unroll
        for (int nf = 0; nf < 4; ++nf)
            bfr[nf] = *(const bf16x8*)&Bs[(wn * 64 + nf * 16 + c) * 40 + g * 8];
#pragma unroll
        for (int mf = 0; mf < 4; ++mf)
#pragma unroll
            for (int nf = 0; nf < 4; ++nf)
                acc[mf][nf] = __builtin_amdgcn_mfma_f32_16x16x32_bf16(
                    af[mf], bfr[nf], acc[mf][nf], 0, 0, 0);
        __syncthreads();
    }
#pragma unroll
    for (int nf = 0; nf < 4; ++nf) {
        int col = col0 + wn * 64 + nf * 16 + c;
        float bz = bias[col];
#pragma unroll
        for (int mf = 0; mf < 4; ++mf)
#pragma unroll
            for (int r = 0; r < 4; ++r) {
                int row = row0 + wm * 64 + mf * 16 + g * 4 + r;
                Cout[(size_t)row * LDC + col] = f2bf((acc[mf][nf][r] + bz) * escale);
            }
    }
}

// ---------------- compact-aware K|V projection per bn ----------------
// grid (4 mtiles, 64 bn, 4 coltiles); early exit past nvp.
__global__ __launch_bounds__(256) void gemm_kv(
    const short* __restrict__ A, const short* __restrict__ W,
    const float* __restrict__ bias, const int* __restrict__ cnt,
    short* __restrict__ C) {
    int bn = blockIdx.y;
    int nvp = (cnt[bn] + 15) & ~15;
    int row0 = blockIdx.x * 128;
    if (row0 >= nvp) return;
    int col0 = blockIdx.z * 128;
    const short* Ab = A + (size_t)bn * 512 * 256;
    short* Cb = C + (size_t)bn * 512 * 512;
    __shared__ __align__(16) short As[128 * 40];
    __shared__ __align__(16) short Bs[128 * 40];
    int tid = threadIdx.x;
    int wid = tid >> 6, lane = tid & 63;
    int wm = wid >> 1, wn = wid & 1;
    int g = lane >> 4, c = lane & 15;
    f32x4 acc[4][4];
#pragma unroll
    for (int i = 0; i < 4; ++i)
#pragma unroll
        for (int j = 0; j < 4; ++j) acc[i][j] = (f32x4){0.f, 0.f, 0.f, 0.f};

    for (int k0 = 0; k0 < 256; k0 += 32) {
#pragma unroll
        for (int it = 0; it < 2; ++it) {
            int idx = tid + it * 256;
            int r = idx >> 2, ch = idx & 3;
            *(bf16x8*)&As[r * 40 + ch * 8] =
                *(const bf16x8*)&Ab[(size_t)(row0 + r) * 256 + k0 + ch * 8];
            *(bf16x8*)&Bs[r * 40 + ch * 8] =
                *(const bf16x8*)&W[(size_t)(col0 + r) * 256 + k0 + ch * 8];
        }
        __syncthreads();
        bf16x8 af[4], bfr[4];
#pragma unroll
        for (int mf = 0; mf < 4; ++mf)
            af[mf] = *(const bf16x8*)&As[(wm * 64 + mf * 16 + c) * 40 + g * 8];
#pragma unroll
        for (int nf = 0; nf < 4; ++nf)
            bfr[nf] = *(const bf16x8*)&Bs[(wn * 64 + nf * 16 + c) * 40 + g * 8];
#pragma unroll
        for (int mf = 0; mf < 4; ++mf)
#pragma unroll
            for (int nf = 0; nf < 4; ++nf)
                acc[mf][nf] = __builtin_amdgcn_mfma_f32_16x16x32_bf16(
                    af[mf], bfr[nf], acc[mf][nf], 0, 0, 0);
        __syncthreads();
    }
#pragma unroll
    for (int nf = 0; nf < 4; ++nf) {
        int col = col0 + wn * 64 + nf * 16 + c;
        float bz = bias[col];
#pragma unroll
        for (int mf = 0; mf < 4; ++mf)
#pragma unroll
            for (int r = 0; r < 4; ++r) {
                int row = row0 + wm * 64 + mf * 16 + g * 4 + r;
                Cb[(size_t)row * 512 + col] = f2bf(acc[mf][nf][r] + bz);
            }
    }
}

// ---------------- fused MFMA attention per (b,n,h), compacted K/V ----------------
// 8 waves; wave owns 64 t rows (4 t-frags). Q prescaled by SCALE2.
template <bool MASKED>
__device__ __forceinline__ void attn_step(
    const short* K_lds, const short* Vt_lds, const bf16x8* qf,
    f32x4 (*ctxa)[2], float* rs, int l0, int nv, int g, int c) {
    bf16x8 ak = *(const bf16x8*)&K_lds[(l0 + c) * 40 + g * 8];
    bf16x4 vb0 = *(const bf16x4*)&Vt_lds[c * 524 + l0 + g * 4];
    bf16x4 vb1 = *(const bf16x4*)&Vt_lds[(16 + c) * 524 + l0 + g * 4];
    int lb = l0 + g * 4;
#pragma unroll
    for (int tf = 0; tf < 4; ++tf) {
        f32x4 s = __builtin_amdgcn_mfma_f32_16x16x32_bf16(
            ak, qf[tf], (f32x4){0.f, 0.f, 0.f, 0.f}, 0, 0, 0);
        float p0 = exp2f(s[0]);
        float p1 = exp2f(s[1]);
        float p2 = exp2f(s[2]);
        float p3 = exp2f(s[3]);
        if (MASKED) {
            p0 = (lb + 0 < nv) ? p0 : 0.f;
            p1 = (lb + 1 < nv) ? p1 : 0.f;
            p2 = (lb + 2 < nv) ? p2 : 0.f;
            p3 = (lb + 3 < nv) ? p3 : 0.f;
        }
        rs[tf] += (p0 + p1) + (p2 + p3);
        bf16x4 pa;
        pa[0] = f2bf(p0); pa[1] = f2bf(p1);
        pa[2] = f2bf(p2); pa[3] = f2bf(p3);
        ctxa[tf][0] = mfma16(pa, vb0, ctxa[tf][0]);
        ctxa[tf][1] = mfma16(pa, vb1, ctxa[tf][1]);
    }
}

__global__ __launch_bounds__(512, 2) void attn_kernel(
    const short* __restrict__ Q, const short* __restrict__ KV2,
    const int* __restrict__ cnt, short* __restrict__ ctx) {
    __shared__ __align__(16) short K_lds[512 * 40];
    __shared__ __align__(16) short Vt_lds[32 * 524];
    int tid = threadIdx.x;
    int bx = blockIdx.x;
    int h = bx & 7, bn = bx >> 3, b = bn >> 3;
    int nv = cnt[bn];
    int nvp = (nv + 15) & ~15;
    const short* kvr = KV2 + (size_t)bn * 512 * 512 + h * 32;
#pragma unroll
    for (int it = 0; it < 4; ++it) {
        int idx = tid + it * 512;
        int i = idx >> 2, ch = idx & 3;
        if (i < nvp) {
            bf16x8 kval = (bf16x8){0, 0, 0, 0, 0, 0, 0, 0};
            bf16x8 vval = (bf16x8){0, 0, 0, 0, 0, 0, 0, 0};
            if (i < nv) {
                kval = *(const bf16x8*)&kvr[(size_t)i * 512 + ch * 8];
                vval = *(const bf16x8*)&kvr[(size_t)i * 512 + 256 + ch * 8];
            }
            *(bf16x8*)&K_lds[i * 40 + ch * 8] = kval;
#pragma unroll
            for (int k = 0; k < 8; ++k)
                Vt_lds[(ch * 8 + k) * 524 + i] = vval[k];
        }
    }
    __syncthreads();

    int wid = tid >> 6, lane = tid & 63;
    int g = lane >> 4, c = lane & 15;
    int t0 = wid * 64;
    const short* qg = Q + ((size_t)b * 512 + t0 + c) * 256 + h * 32 + g * 8;
    bf16x8 qf[4];
#pragma unroll
    for (int tf = 0; tf < 4; ++tf)
        qf[tf] = *(const bf16x8*)&qg[(size_t)tf * 16 * 256];

    f32x4 ctxa[4][2];
    float rs[4];
#pragma unroll
    for (int tf = 0; tf < 4; ++tf) {
        ctxa[tf][0] = (f32x4){0.f, 0.f, 0.f, 0.f};
        ctxa[tf][1] = (f32x4){0.f, 0.f, 0.f, 0.f};
        rs[tf] = 0.f;
    }
    int nfull = nv & ~15;
    for (int l0 = 0; l0 < nfull; l0 += 16)
        attn_step<false>(K_lds, Vt_lds, qf, ctxa, rs, l0, nv, g, c);
    if (nfull < nvp)
        attn_step<true>(K_lds, Vt_lds, qf, ctxa, rs, nfull, nv, g, c);
#ifndef HAVE_MFMA16
    asm volatile("s_nop 7\ns_nop 7");
#endif
#pragma unroll
    for (int tf = 0; tf < 4; ++tf) {
        float r = rs[tf];
        r += __shfl_xor(r, 16);
        r += __shfl_xor(r, 32);
        float inv = 1.f / r;   // rowsum for t-row = c, replicated over groups
#pragma unroll
        for (int rr = 0; rr < 4; ++rr) {
            float invr = __shfl(inv, (lane & 48) | (g * 4 + rr));
            ctxa[tf][0][rr] *= invr;
            ctxa[tf][1][rr] *= invr;
        }
    }
    __syncthreads();   // all waves done with K_lds/Vt_lds; reuse K_lds as staging
#pragma unroll
    for (int tf = 0; tf < 4; ++tf)
#pragma unroll
        for (int df = 0; df < 2; ++df)
#pragma unroll
            for (int rr = 0; rr < 4; ++rr)
                K_lds[(t0 + tf * 16 + g * 4 + rr) * 40 + df * 16 + c] =
                    f2bf(ctxa[tf][df][rr]);
    __syncthreads();
    short* cg = ctx + (size_t)bn * 512 * 256 + h * 32;
#pragma unroll
    for (int it = 0; it < 4; ++it) {
        int idx = tid + it * 512;
        int l = idx >> 2, ch = idx & 3;
        *(bf16x8*)&cg[(size_t)l * 256 + ch * 8] =
            *(const bf16x8*)&K_lds[l * 40 + ch * 8];
    }
}

// ---------------- final: out = mean_n (x_pe + attn) * edge ----------------
__global__ __launch_bounds__(256) void final_kernel(
    const float* __restrict__ xpe, const short* __restrict__ attn,
    const float* __restrict__ nbr_edge, const float* __restrict__ Wedge,
    const float* __restrict__ bedge, float* __restrict__ out) {
    int row = blockIdx.x;
    int tid = threadIdx.x;
    int b = row >> 9, t = row & 511;
    float xp = xpe[(size_t)row * 256 + tid];
    float we[8];
#pragma unroll
    for (int cc = 0; cc < 8; ++cc) we[cc] = Wedge[tid * 8 + cc];
    float be = bedge[tid];
    float acc = 0.f;
#pragma unroll
    for (int n = 0; n < 8; ++n) {
        size_t bn = (size_t)(b * 8 + n);
        float av = bf2f(attn[(bn * 512 + t) * 256 + tid]);
        float eg = be;
#pragma unroll
        for (int cc = 0; cc < 8; ++cc)
            eg = fmaf(nbr_edge[(bn * 8 + cc) * 512 + t], we[cc], eg);
        acc = fmaf(xp + av, eg, acc);
    }
    out[(size_t)row * 256 + tid] = acc * 0.125f;
}

extern "C" void kernel_launch(void* const* d_in, const int* in_sizes, int n_in,
                              void* d_out, int out_size, void* d_ws, size_t ws_size,
                              hipStream_t stream) {
    const float* x        = (const float*)d_in[0];
    const float* nbr_ts   = (const float*)d_in[1];
    const float* nbr_aux  = (const float*)d_in[2];
    const float* nbr_edge = (const float*)d_in[3];
    const int*   mask     = (const int*)d_in[4];
    const float* Wts  = (const float*)d_in[5];
    const float* bts  = (const float*)d_in[6];
    const float* Waux = (const float*)d_in[7];
    const float* baux = (const float*)d_in[8];
    const float* Wedge= (const float*)d_in[9];
    const float* bedge= (const float*)d_in[10];
    const float* ln_a = (const float*)d_in[11];
    const float* ln_b = (const float*)d_in[12];
    const float* Wq = (const float*)d_in[13];
    const float* bq = (const float*)d_in[14];
    const float* Wk = (const float*)d_in[15];
    const float* bk = (const float*)d_in[16];
    const float* Wv = (const float*)d_in[17];
    const float* bv = (const float*)d_in[18];
    const float* Wo = (const float*)d_in[19];
    const float* bo = (const float*)d_in[20];
    float* out = (float*)d_out;

    char* W = (char*)d_ws;
    float* pe_f    = (float*)(W);                 // 512 KB
    float* xpe_f   = (float*)(W + 524288);        // 4 MB
    short* qin_bf  = (short*)(W + 4718592);       // 2 MB
    short* q_bf    = (short*)(W + 6815744);       // 2 MB
    short* kvc_bf  = (short*)(W + 8912896);       // 16 MB (compacted kv embed)
    short* kv2c_bf = (short*)(W + 25690112);      // 32 MB (compacted K|V, LDC 512)
    short* ctx_bf  = (short*)(W + 59244544);      // 16 MB
    short* attn_bf = (short*)(W + 76021760);      // 16 MB
    short* w_bf    = (short*)(W + 92798976);      // 512 KB
    short* W2_bf   = (short*)(W + 93323264);      // 48 KB
    float* bias2_f = (float*)(W + 93372416);      // 1 KB
    float* bkv_f   = (float*)(W + 93373440);      // 2 KB
    int*   pos     = (int*)  (W + 93375488);      // 128 KB
    int*   cnt     = (int*)  (W + 93506560);      // 256 B
    short* wq_bf = w_bf;
    short* wk_bf = w_bf + 65536;   // wk,wv contiguous => one [512][256] matrix
    short* wo_bf = w_bf + 196608;

    prep_kernel<<<864, 256, 0, stream>>>(Wq, Wk, Wv, Wo, Wts, Waux, bts, baux,
                                         bk, bv, w_bf, W2_bf, bias2_f, bkv_f,
                                         pe_f);
    pos_kernel<<<64, 512, 0, stream>>>(mask, pos, cnt);
    kv_gemm<<<dim3(64, 4), 512, 0, stream>>>(nbr_ts, nbr_aux, W2_bf, bias2_f,
                                             pe_f, pos, kvc_bf);
    ln_kernel<<<4096, 256, 0, stream>>>(x, pe_f, ln_a, ln_b, xpe_f, qin_bf);
    gemm_bf16<256><<<dim3(32, 2), 256, 0, stream>>>(qin_bf, wq_bf, bq, q_bf,
                                                    (float)SCALE2);
    gemm_kv<<<dim3(4, 64, 4), 256, 0, stream>>>(kvc_bf, wk_bf, bkv_f, cnt,
                                                kv2c_bf);
    attn_kernel<<<512, 512, 0, stream>>>(q_bf, kv2c_bf, cnt, ctx_bf);
    gemm_bf16<256><<<dim3(256, 2), 256, 0, stream>>>(ctx_bf, wo_bf, bo, attn_bf,
                                                     1.0f);
    final_kernel<<<4096, 256, 0, stream>>>(xpe_f, attn_bf, nbr_edge, Wedge,
                                           bedge, out);
}

// Round 7
// 114.601 us; speedup vs baseline: 3.5152x; 1.1140x over previous
//
#include <hip/hip_runtime.h>
#include <hip/hip_bf16.h>
#include <math.h>

// Dims: B=8, N=8, T=512, L=512, d=256, H=8, dk=32
typedef __attribute__((ext_vector_type(8))) short bf16x8;
typedef __attribute__((ext_vector_type(4))) short bf16x4;
typedef __attribute__((ext_vector_type(4))) float f32x4;

__device__ __forceinline__ short f2bf(float f) {
    return (short)__builtin_bit_cast(unsigned short, __float2bfloat16(f));
}
__device__ __forceinline__ float bf2f(short s) {
    return __builtin_bit_cast(float, ((unsigned)(unsigned short)s) << 16);
}
__device__ __forceinline__ unsigned pk2bf(float a, float b) {
    return ((unsigned)(unsigned short)f2bf(b) << 16) |
           (unsigned)(unsigned short)f2bf(a);
}

#if defined(__has_builtin)
#if __has_builtin(__builtin_amdgcn_mfma_f32_16x16x16bf16_1k)
#define HAVE_MFMA16 1
#endif
#endif

__device__ __forceinline__ f32x4 mfma16(bf16x4 a, bf16x4 b, f32x4 c) {
#ifdef HAVE_MFMA16
    return __builtin_amdgcn_mfma_f32_16x16x16bf16_1k(a, b, c, 0, 0, 0);
#else
    f32x4 d;
    asm volatile("v_mfma_f32_16x16x16_bf16 %0, %1, %2, %3"
                 : "=v"(d) : "v"(a), "v"(b), "v"(c));
    return d;
#endif
}

#define SCALE2 0.25503482403f   // (1/sqrt(32)) * log2(e)

// ---------------- setup: weights->bf16 | W2/bias2/bkv | PE | pos scan | LN ----------------
// 512 threads. bid ranges: [0,128) wconv, [128,176) W2, [176,432) pe,
// [432,496) pos, [496,2544) LN (2 rows/block, pe inline).
__global__ __launch_bounds__(512) void setup_kernel(
    const float* __restrict__ Wq, const float* __restrict__ Wk,
    const float* __restrict__ Wv, const float* __restrict__ Wo,
    const float* __restrict__ Wts, const float* __restrict__ Waux,
    const float* __restrict__ bts, const float* __restrict__ baux,
    const float* __restrict__ bk, const float* __restrict__ bv,
    const float* __restrict__ x, const float* __restrict__ ln_a,
    const float* __restrict__ ln_b, const int* __restrict__ mask,
    short* __restrict__ wout, short* __restrict__ W2,
    float* __restrict__ bias2, float* __restrict__ bkv,
    float* __restrict__ pe, int* __restrict__ pos, int* __restrict__ cnt,
    short* __restrict__ xpe_bf, short* __restrict__ qin) {
    __shared__ float redA[8];
    __shared__ float redB[8];
    __shared__ int wsum[8];
    int bid = blockIdx.x, tid = threadIdx.x;
    if (bid < 128) {
        int i = bid * 512 + tid;
        wout[i]          = f2bf(Wq[i]);
        wout[65536 + i]  = f2bf(Wk[i]);
        wout[131072 + i] = f2bf(Wv[i]);
        wout[196608 + i] = f2bf(Wo[i]);
    } else if (bid < 176) {
        int idx = (bid - 128) * 512 + tid;   // 24576
        int e = idx / 96, ch = idx - e * 96;
        float v = 0.f;
        if (ch < 64) { if (e < 192) v = Wts[e * 64 + ch]; }
        else if (ch < 80) { if (e >= 192) v = Waux[(e - 192) * 16 + (ch - 64)]; }
        W2[idx] = f2bf(v);
        if (idx < 256) bias2[idx] = idx < 192 ? bts[idx] : baux[idx - 192];
        if (idx < 512) bkv[idx] = idx < 256 ? bk[idx] : bv[idx - 256];
    } else if (bid < 432) {
        int t = (bid - 176) * 2 + (tid >> 8);
        int dd = tid & 255;
        int i = dd >> 1;
        float div = expf((float)(2 * i) * (-9.210340371976184f / 256.0f));
        float ang = (float)t * div;
        pe[t * 256 + dd] = (dd & 1) ? cosf(ang) : sinf(ang);
    } else if (bid < 496) {
        int bn = bid - 432;
        int lane = tid & 63, wid = tid >> 6;
        int m = mask[bn * 512 + tid] != 0;
        int v = m;
#pragma unroll
        for (int off = 1; off < 64; off <<= 1) {
            int t = __shfl_up(v, off);
            if (lane >= off) v += t;
        }
        if (lane == 63) wsum[wid] = v;
        __syncthreads();
        int base = 0;
#pragma unroll
        for (int w = 0; w < 8; ++w) base += (w < wid) ? wsum[w] : 0;
        pos[bn * 512 + tid] = m ? (base + v - 1) : -1;
        if (tid == 511) cnt[bn] = base + v;
    } else {
        int half = tid >> 8;
        int d = tid & 255;
        int row = (bid - 496) * 2 + half;
        int t = row & 511;
        int i = d >> 1;
        float div = expf((float)(2 * i) * (-9.210340371976184f / 256.0f));
        float ang = (float)t * div;
        float pev = (d & 1) ? cosf(ang) : sinf(ang);
        float v = x[(size_t)row * 256 + d] + pev;
        xpe_bf[(size_t)row * 256 + d] = f2bf(v);
        float s = v;
#pragma unroll
        for (int off = 32; off > 0; off >>= 1) s += __shfl_xor(s, off);
        if ((tid & 63) == 0) redA[tid >> 6] = s;
        __syncthreads();
        int rb = half * 4;
        float mu = (redA[rb] + redA[rb + 1] + redA[rb + 2] + redA[rb + 3]) *
                   (1.0f / 256.0f);
        float dv = v - mu;
        float s2 = dv * dv;
#pragma unroll
        for (int off = 32; off > 0; off >>= 1) s2 += __shfl_xor(s2, off);
        if ((tid & 63) == 0) redB[tid >> 6] = s2;
        __syncthreads();
        float var = (redB[rb] + redB[rb + 1] + redB[rb + 2] + redB[rb + 3]) *
                    (1.0f / 255.0f);
        float sd = sqrtf(var);
        qin[(size_t)row * 256 + d] = f2bf(ln_a[d] * dv / (sd + 1e-6f) + ln_b[d]);
    }
}

// ---------------- kv embed as MFMA GEMM over K=96, scatter to compacted rows ----------------
__global__ __launch_bounds__(512, 2) void kv_gemm(
    const float* __restrict__ nbr_ts, const float* __restrict__ nbr_aux,
    const short* __restrict__ W2, const float* __restrict__ bias2,
    const float* __restrict__ pe, const int* __restrict__ pos,
    short* __restrict__ kvc) {
    __shared__ __align__(16) float S1[64 * 132];
    __shared__ __align__(16) float S2[16 * 132];
    __shared__ __align__(16) short A_lds[128 * 104];
    int tid = threadIdx.x;
    int bn = blockIdx.x, l0 = blockIdx.y * 128;
    const float* tsb = nbr_ts + (size_t)bn * 64 * 512;
    const float* axb = nbr_aux + (size_t)bn * 16 * 512;
#pragma unroll
    for (int it = 0; it < 4; ++it) {
        int idx = tid + it * 512;
        int cc = idx >> 5, lq = idx & 31;
        *(float4*)&S1[cc * 132 + lq * 4] =
            *(const float4*)&tsb[(size_t)cc * 512 + l0 + lq * 4];
    }
    {
        int cc = tid >> 5, lq = tid & 31;
        *(float4*)&S2[cc * 132 + lq * 4] =
            *(const float4*)&axb[(size_t)cc * 512 + l0 + lq * 4];
    }
    __syncthreads();
#pragma unroll
    for (int p = 0; p < 3; ++p) {
        int tk = tid + p * 512;
        int l = tk & 127, chunk = tk >> 7;
        union { bf16x8 v; unsigned u[4]; } v8;
        if (chunk < 8) {
#pragma unroll
            for (int i = 0; i < 4; ++i)
                v8.u[i] = pk2bf(S1[(chunk * 8 + 2 * i) * 132 + l],
                                S1[(chunk * 8 + 2 * i + 1) * 132 + l]);
        } else if (chunk < 10) {
#pragma unroll
            for (int i = 0; i < 4; ++i)
                v8.u[i] = pk2bf(S2[((chunk - 8) * 8 + 2 * i) * 132 + l],
                                S2[((chunk - 8) * 8 + 2 * i + 1) * 132 + l]);
        } else {
#pragma unroll
            for (int i = 0; i < 4; ++i) v8.u[i] = 0;
        }
        *(bf16x8*)&A_lds[l * 104 + chunk * 8] = v8.v;
    }
    __syncthreads();
    int wid = tid >> 6, lane = tid & 63;
    int g = lane >> 4, c = lane & 15;
    int lm = wid >> 2, le = wid & 3;
    bf16x8 wf[4][3];
#pragma unroll
    for (int nf = 0; nf < 4; ++nf)
#pragma unroll
        for (int ks = 0; ks < 3; ++ks)
            wf[nf][ks] = *(const bf16x8*)&W2[(size_t)(le * 64 + nf * 16 + c) * 96 +
                                             ks * 32 + g * 8];
    f32x4 acc[4][4];
#pragma unroll
    for (int i = 0; i < 4; ++i)
#pragma unroll
        for (int j = 0; j < 4; ++j) acc[i][j] = (f32x4){0.f, 0.f, 0.f, 0.f};
#pragma unroll
    for (int ks = 0; ks < 3; ++ks) {
#pragma unroll
        for (int mf = 0; mf < 4; ++mf) {
            bf16x8 af = *(const bf16x8*)&A_lds[(lm * 64 + mf * 16 + c) * 104 +
                                               ks * 32 + g * 8];
#pragma unroll
            for (int nf = 0; nf < 4; ++nf)
                acc[mf][nf] = __builtin_amdgcn_mfma_f32_16x16x32_bf16(
                    af, wf[nf][ks], acc[mf][nf], 0, 0, 0);
        }
    }
    float b2c[4];
#pragma unroll
    for (int nf = 0; nf < 4; ++nf) b2c[nf] = bias2[le * 64 + nf * 16 + c];
    short* kvb = kvc + (size_t)bn * 512 * 256;
    const int* posb = pos + bn * 512 + l0;
#pragma unroll
    for (int mf = 0; mf < 4; ++mf) {
#pragma unroll
        for (int r = 0; r < 4; ++r) {
            int lr = lm * 64 + mf * 16 + g * 4 + r;
            int p = posb[lr];
            if (p >= 0) {
#pragma unroll
                for (int nf = 0; nf < 4; ++nf) {
                    int e = le * 64 + nf * 16 + c;
                    kvb[(size_t)p * 256 + e] =
                        f2bf(acc[mf][nf][r] + b2c[nf] +
                             pe[(size_t)(l0 + lr) * 256 + e]);
                }
            }
        }
    }
}

// ---------------- merged q-projection + compact K|V projection ----------------
// bx<64: q GEMM (rows 4096, cols 256, escale SCALE2).
// bx>=64: per-bn K|V GEMM (LDC 512), early exit past nvp.
__global__ __launch_bounds__(256) void proj_gemm(
    const short* __restrict__ qin, const short* __restrict__ kvc,
    const short* __restrict__ wq, const short* __restrict__ wkv,
    const float* __restrict__ bq, const float* __restrict__ bkv,
    const int* __restrict__ cnt, short* __restrict__ qout,
    short* __restrict__ kv2) {
    int bx = blockIdx.x;
    const short* A; const short* Wm; const float* bias; short* C;
    int row0, col0, LDC; float esc;
    if (bx < 64) {
        row0 = (bx >> 1) * 128; col0 = (bx & 1) * 128;
        A = qin; Wm = wq; bias = bq; C = qout; LDC = 256; esc = SCALE2;
    } else {
        int idx = bx - 64;               // 1024 = bn(64) x mt(4) x ct(4)
        int bn = idx >> 4, mt = (idx >> 2) & 3, ct = idx & 3;
        int nvp = (cnt[bn] + 15) & ~15;
        row0 = mt * 128;
        if (row0 >= nvp) return;
        col0 = ct * 128;
        A = kvc + (size_t)bn * 512 * 256; Wm = wkv; bias = bkv;
        C = kv2 + (size_t)bn * 512 * 512; LDC = 512; esc = 1.0f;
    }
    __shared__ __align__(16) short As[128 * 40];
    __shared__ __align__(16) short Bs[128 * 40];
    int tid = threadIdx.x;
    int wid = tid >> 6, lane = tid & 63;
    int wm = wid >> 1, wn = wid & 1;
    int g = lane >> 4, c = lane & 15;
    f32x4 acc[4][4];
#pragma unroll
    for (int i = 0; i < 4; ++i)
#pragma unroll
        for (int j = 0; j < 4; ++j) acc[i][j] = (f32x4){0.f, 0.f, 0.f, 0.f};

    for (int k0 = 0; k0 < 256; k0 += 32) {
#pragma unroll
        for (int it = 0; it < 2; ++it) {
            int idx = tid + it * 256;
            int r = idx >> 2, ch = idx & 3;
            *(bf16x8*)&As[r * 40 + ch * 8] =
                *(const bf16x8*)&A[(size_t)(row0 + r) * 256 + k0 + ch * 8];
            *(bf16x8*)&Bs[r * 40 + ch * 8] =
                *(const bf16x8*)&Wm[(size_t)(col0 + r) * 256 + k0 + ch * 8];
        }
        __syncthreads();
        bf16x8 af[4], bfr[4];
#pragma unroll
        for (int mf = 0; mf < 4; ++mf)
            af[mf] = *(const bf16x8*)&As[(wm * 64 + mf * 16 + c) * 40 + g * 8];
#pragma unroll
        for (int nf = 0; nf < 4; ++nf)
            bfr[nf] = *(const bf16x8*)&Bs[(wn * 64 + nf * 16 + c) * 40 + g * 8];
#pragma unroll
        for (int mf = 0; mf < 4; ++mf)
#pragma unroll
            for (int nf = 0; nf < 4; ++nf)
                acc[mf][nf] = __builtin_amdgcn_mfma_f32_16x16x32_bf16(
                    af[mf], bfr[nf], acc[mf][nf], 0, 0, 0);
        __syncthreads();
    }
#pragma unroll
    for (int nf = 0; nf < 4; ++nf) {
        int col = col0 + wn * 64 + nf * 16 + c;
        float bz = bias[col];
#pragma unroll
        for (int mf = 0; mf < 4; ++mf)
#pragma unroll
            for (int r = 0; r < 4; ++r) {
                int row = row0 + wm * 64 + mf * 16 + g * 4 + r;
                C[(size_t)row * LDC + col] = f2bf((acc[mf][nf][r] + bz) * esc);
            }
    }
}

// ---------------- bf16 MFMA GEMM for Wo: C = A @ W^T + bias (bf16 out) ----------------
__global__ __launch_bounds__(256) void gemm_wo(
    const short* __restrict__ A, const short* __restrict__ W,
    const float* __restrict__ bias, short* __restrict__ Cout) {
    __shared__ __align__(16) short As[128 * 40];
    __shared__ __align__(16) short Bs[128 * 40];
    int tid = threadIdx.x;
    int row0 = blockIdx.x * 128, col0 = blockIdx.y * 128;
    int wid = tid >> 6, lane = tid & 63;
    int wm = wid >> 1, wn = wid & 1;
    int g = lane >> 4, c = lane & 15;
    f32x4 acc[4][4];
#pragma unroll
    for (int i = 0; i < 4; ++i)
#pragma unroll
        for (int j = 0; j < 4; ++j) acc[i][j] = (f32x4){0.f, 0.f, 0.f, 0.f};

    for (int k0 = 0; k0 < 256; k0 += 32) {
#pragma unroll
        for (int it = 0; it < 2; ++it) {
            int idx = tid + it * 256;
            int r = idx >> 2, ch = idx & 3;
            *(bf16x8*)&As[r * 40 + ch * 8] =
                *(const bf16x8*)&A[(size_t)(row0 + r) * 256 + k0 + ch * 8];
            *(bf16x8*)&Bs[r * 40 + ch * 8] =
                *(const bf16x8*)&W[(size_t)(col0 + r) * 256 + k0 + ch * 8];
        }
        __syncthreads();
        bf16x8 af[4], bfr[4];
#pragma unroll
        for (int mf = 0; mf < 4; ++mf)
            af[mf] = *(const bf16x8*)&As[(wm * 64 + mf * 16 + c) * 40 + g * 8];
#pragma unroll
        for (int nf = 0; nf < 4; ++nf)
            bfr[nf] = *(const bf16x8*)&Bs[(wn * 64 + nf * 16 + c) * 40 + g * 8];
#pragma unroll
        for (int mf = 0; mf < 4; ++mf)
#pragma unroll
            for (int nf = 0; nf < 4; ++nf)
                acc[mf][nf] = __builtin_amdgcn_mfma_f32_16x16x32_bf16(
                    af[mf], bfr[nf], acc[mf][nf], 0, 0, 0);
        __syncthreads();
    }
#pragma unroll
    for (int nf = 0; nf < 4; ++nf) {
        int col = col0 + wn * 64 + nf * 16 + c;
        float bz = bias[col];
#pragma unroll
        for (int mf = 0; mf < 4; ++mf)
#pragma unroll
            for (int r = 0; r < 4; ++r) {
                int row = row0 + wm * 64 + mf * 16 + g * 4 + r;
                Cout[(size_t)row * 256 + col] = f2bf(acc[mf][nf][r] + bz);
            }
    }
}

// ---------------- fused MFMA attention per (b,n,h), compacted K/V ----------------
template <bool MASKED>
__device__ __forceinline__ void attn_step(
    const short* K_lds, const short* Vt_lds, const bf16x8* qf,
    f32x4 (*ctxa)[2], f32x4* rsv, int l0, int nv, int g, int c) {
    bf16x8 ak = *(const bf16x8*)&K_lds[(l0 + c) * 40 + g * 8];
    bf16x4 vb0 = *(const bf16x4*)&Vt_lds[c * 524 + l0 + g * 4];
    bf16x4 vb1 = *(const bf16x4*)&Vt_lds[(16 + c) * 524 + l0 + g * 4];
    int lb = l0 + g * 4;
#pragma unroll
    for (int tf = 0; tf < 4; ++tf) {
        f32x4 s = __builtin_amdgcn_mfma_f32_16x16x32_bf16(
            ak, qf[tf], (f32x4){0.f, 0.f, 0.f, 0.f}, 0, 0, 0);
        float p0 = exp2f(s[0]);
        float p1 = exp2f(s[1]);
        float p2 = exp2f(s[2]);
        float p3 = exp2f(s[3]);
        if (MASKED) {
            p0 = (lb + 0 < nv) ? p0 : 0.f;
            p1 = (lb + 1 < nv) ? p1 : 0.f;
            p2 = (lb + 2 < nv) ? p2 : 0.f;
            p3 = (lb + 3 < nv) ? p3 : 0.f;
        }
        rsv[tf] += (f32x4){p0, p1, p2, p3};
        union { bf16x4 v; unsigned u[2]; } pu;
        pu.u[0] = pk2bf(p0, p1);
        pu.u[1] = pk2bf(p2, p3);
        __builtin_amdgcn_s_setprio(1);
        ctxa[tf][0] = mfma16(pu.v, vb0, ctxa[tf][0]);
        ctxa[tf][1] = mfma16(pu.v, vb1, ctxa[tf][1]);
        __builtin_amdgcn_s_setprio(0);
    }
}

__global__ __launch_bounds__(512, 2) void attn_kernel(
    const short* __restrict__ Q, const short* __restrict__ KV2,
    const int* __restrict__ cnt, short* __restrict__ ctx) {
    __shared__ __align__(16) short K_lds[512 * 40];
    __shared__ __align__(16) short Vt_lds[32 * 524];
    int tid = threadIdx.x;
    int bx = blockIdx.x;
    int h = bx & 7, bn = bx >> 3, b = bn >> 3;
    int nv = cnt[bn];
    int nvp = (nv + 15) & ~15;
    const short* kvr = KV2 + (size_t)bn * 512 * 512 + h * 32;
#pragma unroll
    for (int it = 0; it < 4; ++it) {
        int idx = tid + it * 512;
        int i = idx >> 2, ch = idx & 3;
        if (i < nvp) {
            bf16x8 kval = (bf16x8){0, 0, 0, 0, 0, 0, 0, 0};
            bf16x8 vval = (bf16x8){0, 0, 0, 0, 0, 0, 0, 0};
            if (i < nv) {
                kval = *(const bf16x8*)&kvr[(size_t)i * 512 + ch * 8];
                vval = *(const bf16x8*)&kvr[(size_t)i * 512 + 256 + ch * 8];
            }
            *(bf16x8*)&K_lds[i * 40 + ch * 8] = kval;
#pragma unroll
            for (int k = 0; k < 8; ++k)
                Vt_lds[(ch * 8 + k) * 524 + i] = vval[k];
        }
    }
    __syncthreads();

    int wid = tid >> 6, lane = tid & 63;
    int g = lane >> 4, c = lane & 15;
    int t0 = wid * 64;
    const short* qg = Q + ((size_t)b * 512 + t0 + c) * 256 + h * 32 + g * 8;
    bf16x8 qf[4];
#pragma unroll
    for (int tf = 0; tf < 4; ++tf)
        qf[tf] = *(const bf16x8*)&qg[(size_t)tf * 16 * 256];

    f32x4 ctxa[4][2];
    f32x4 rsv[4];
#pragma unroll
    for (int tf = 0; tf < 4; ++tf) {
        ctxa[tf][0] = (f32x4){0.f, 0.f, 0.f, 0.f};
        ctxa[tf][1] = (f32x4){0.f, 0.f, 0.f, 0.f};
        rsv[tf] = (f32x4){0.f, 0.f, 0.f, 0.f};
    }
    int nfull = nv & ~15;
    for (int l0 = 0; l0 < nfull; l0 += 16)
        attn_step<false>(K_lds, Vt_lds, qf, ctxa, rsv, l0, nv, g, c);
    if (nfull < nvp)
        attn_step<true>(K_lds, Vt_lds, qf, ctxa, rsv, nfull, nv, g, c);
#ifndef HAVE_MFMA16
    asm volatile("s_nop 7\ns_nop 7");
#endif
#pragma unroll
    for (int tf = 0; tf < 4; ++tf) {
        float r = (rsv[tf][0] + rsv[tf][1]) + (rsv[tf][2] + rsv[tf][3]);
        r += __shfl_xor(r, 16);
        r += __shfl_xor(r, 32);
        float inv = 1.f / r;   // rowsum for t-row = c, replicated over groups
#pragma unroll
        for (int rr = 0; rr < 4; ++rr) {
            float invr = __shfl(inv, (lane & 48) | (g * 4 + rr));
            ctxa[tf][0][rr] *= invr;
            ctxa[tf][1][rr] *= invr;
        }
    }
    __syncthreads();   // all waves done with K_lds/Vt_lds; reuse K_lds as staging
#pragma unroll
    for (int tf = 0; tf < 4; ++tf)
#pragma unroll
        for (int df = 0; df < 2; ++df)
#pragma unroll
            for (int rr = 0; rr < 4; ++rr)
                K_lds[(t0 + tf * 16 + g * 4 + rr) * 40 + df * 16 + c] =
                    f2bf(ctxa[tf][df][rr]);
    __syncthreads();
    short* cg = ctx + (size_t)bn * 512 * 256 + h * 32;
#pragma unroll
    for (int it = 0; it < 4; ++it) {
        int idx = tid + it * 512;
        int l = idx >> 2, ch = idx & 3;
        *(bf16x8*)&cg[(size_t)l * 256 + ch * 8] =
            *(const bf16x8*)&K_lds[l * 40 + ch * 8];
    }
}

// ---------------- final: out = mean_n (x_pe + attn) * edge ----------------
__global__ __launch_bounds__(256) void final_kernel(
    const short* __restrict__ xpe, const short* __restrict__ attn,
    const float* __restrict__ nbr_edge, const float* __restrict__ Wedge,
    const float* __restrict__ bedge, float* __restrict__ out) {
    int row = blockIdx.x;
    int tid = threadIdx.x;
    int b = row >> 9, t = row & 511;
    float xp = bf2f(xpe[(size_t)row * 256 + tid]);
    float we[8];
#pragma unroll
    for (int cc = 0; cc < 8; ++cc) we[cc] = Wedge[tid * 8 + cc];
    float be = bedge[tid];
    float acc = 0.f;
#pragma unroll
    for (int n = 0; n < 8; ++n) {
        size_t bn = (size_t)(b * 8 + n);
        float av = bf2f(attn[(bn * 512 + t) * 256 + tid]);
        float eg = be;
#pragma unroll
        for (int cc = 0; cc < 8; ++cc)
            eg = fmaf(nbr_edge[(bn * 8 + cc) * 512 + t], we[cc], eg);
        acc = fmaf(xp + av, eg, acc);
    }
    out[(size_t)row * 256 + tid] = acc * 0.125f;
}

extern "C" void kernel_launch(void* const* d_in, const int* in_sizes, int n_in,
                              void* d_out, int out_size, void* d_ws, size_t ws_size,
                              hipStream_t stream) {
    const float* x        = (const float*)d_in[0];
    const float* nbr_ts   = (const float*)d_in[1];
    const float* nbr_aux  = (const float*)d_in[2];
    const float* nbr_edge = (const float*)d_in[3];
    const int*   mask     = (const int*)d_in[4];
    const float* Wts  = (const float*)d_in[5];
    const float* bts  = (const float*)d_in[6];
    const float* Waux = (const float*)d_in[7];
    const float* baux = (const float*)d_in[8];
    const float* Wedge= (const float*)d_in[9];
    const float* bedge= (const float*)d_in[10];
    const float* ln_a = (const float*)d_in[11];
    const float* ln_b = (const float*)d_in[12];
    const float* Wq = (const float*)d_in[13];
    const float* bq = (const float*)d_in[14];
    const float* Wk = (const float*)d_in[15];
    const float* bk = (const float*)d_in[16];
    const float* Wv = (const float*)d_in[17];
    const float* bv = (const float*)d_in[18];
    const float* Wo = (const float*)d_in[19];
    const float* bo = (const float*)d_in[20];
    float* out = (float*)d_out;

    char* W = (char*)d_ws;
    float* pe_f    = (float*)(W);                 // 512 KB
    short* xpe_bf  = (short*)(W + 524288);        // 2 MB
    short* qin_bf  = (short*)(W + 4718592);       // 2 MB
    short* q_bf    = (short*)(W + 6815744);       // 2 MB
    short* kvc_bf  = (short*)(W + 8912896);       // 16 MB (compacted kv embed)
    short* kv2c_bf = (short*)(W + 25690112);      // 32 MB (compacted K|V, LDC 512)
    short* ctx_bf  = (short*)(W + 59244544);      // 16 MB
    short* attn_bf = (short*)(W + 76021760);      // 16 MB
    short* w_bf    = (short*)(W + 92798976);      // 512 KB
    short* W2_bf   = (short*)(W + 93323264);      // 48 KB
    float* bias2_f = (float*)(W + 93372416);      // 1 KB
    float* bkv_f   = (float*)(W + 93373440);      // 2 KB
    int*   pos     = (int*)  (W + 93375488);      // 128 KB
    int*   cnt     = (int*)  (W + 93506560);      // 256 B
    short* wq_bf = w_bf;
    short* wkv_bf = w_bf + 65536;  // wk,wv contiguous => one [512][256] matrix
    short* wo_bf = w_bf + 196608;

    setup_kernel<<<2544, 512, 0, stream>>>(
        Wq, Wk, Wv, Wo, Wts, Waux, bts, baux, bk, bv, x, ln_a, ln_b, mask,
        w_bf, W2_bf, bias2_f, bkv_f, pe_f, pos, cnt, xpe_bf, qin_bf);
    kv_gemm<<<dim3(64, 4), 512, 0, stream>>>(nbr_ts, nbr_aux, W2_bf, bias2_f,
                                             pe_f, pos, kvc_bf);
    proj_gemm<<<1088, 256, 0, stream>>>(qin_bf, kvc_bf, wq_bf, wkv_bf, bq,
                                        bkv_f, cnt, q_bf, kv2c_bf);
    attn_kernel<<<512, 512, 0, stream>>>(q_bf, kv2c_bf, cnt, ctx_bf);
    gemm_wo<<<dim3(256, 2), 256, 0, stream>>>(ctx_bf, wo_bf, bo, attn_bf);
    final_kernel<<<4096, 256, 0, stream>>>(xpe_bf, attn_bf, nbr_edge, Wedge,
                                           bedge, out);
}

// Round 8
// 104.712 us; speedup vs baseline: 3.8471x; 1.0944x over previous
//
#include <hip/hip_runtime.h>
#include <hip/hip_bf16.h>
#include <math.h>

// Dims: B=8, N=8, T=512, L=512, d=256, H=8, dk=32
typedef __attribute__((ext_vector_type(8))) short bf16x8;
typedef __attribute__((ext_vector_type(4))) short bf16x4;
typedef __attribute__((ext_vector_type(4))) float f32x4;

__device__ __forceinline__ short f2bf(float f) {
    return (short)__builtin_bit_cast(unsigned short, __float2bfloat16(f));
}
__device__ __forceinline__ float bf2f(short s) {
    return __builtin_bit_cast(float, ((unsigned)(unsigned short)s) << 16);
}
__device__ __forceinline__ unsigned pk2bf(float a, float b) {
    return ((unsigned)(unsigned short)f2bf(b) << 16) |
           (unsigned)(unsigned short)f2bf(a);
}

#if defined(__has_builtin)
#if __has_builtin(__builtin_amdgcn_mfma_f32_16x16x16bf16_1k)
#define HAVE_MFMA16 1
#endif
#endif

__device__ __forceinline__ f32x4 mfma16(bf16x4 a, bf16x4 b, f32x4 c) {
#ifdef HAVE_MFMA16
    return __builtin_amdgcn_mfma_f32_16x16x16bf16_1k(a, b, c, 0, 0, 0);
#else
    f32x4 d;
    asm volatile("v_mfma_f32_16x16x16_bf16 %0, %1, %2, %3"
                 : "=v"(d) : "v"(a), "v"(b), "v"(c));
    return d;
#endif
}

#define SCALE2 0.25503482403f   // (1/sqrt(32)) * log2(e)

// ---------------- setup: weights->bf16 | W2/bias2/bkv | PE | pos scan | LN ----------------
__global__ __launch_bounds__(512) void setup_kernel(
    const float* __restrict__ Wq, const float* __restrict__ Wk,
    const float* __restrict__ Wv, const float* __restrict__ Wo,
    const float* __restrict__ Wts, const float* __restrict__ Waux,
    const float* __restrict__ bts, const float* __restrict__ baux,
    const float* __restrict__ bk, const float* __restrict__ bv,
    const float* __restrict__ x, const float* __restrict__ ln_a,
    const float* __restrict__ ln_b, const int* __restrict__ mask,
    short* __restrict__ wout, short* __restrict__ W2,
    float* __restrict__ bias2, float* __restrict__ bkv,
    float* __restrict__ pe, int* __restrict__ pos, int* __restrict__ cnt,
    short* __restrict__ xpe_bf, short* __restrict__ qin) {
    __shared__ float redA[8];
    __shared__ float redB[8];
    __shared__ int wsum[8];
    int bid = blockIdx.x, tid = threadIdx.x;
    if (bid < 128) {
        int i = bid * 512 + tid;
        wout[i]          = f2bf(Wq[i]);
        wout[65536 + i]  = f2bf(Wk[i]);
        wout[131072 + i] = f2bf(Wv[i]);
        wout[196608 + i] = f2bf(Wo[i]);
    } else if (bid < 176) {
        int idx = (bid - 128) * 512 + tid;   // 24576
        int e = idx / 96, ch = idx - e * 96;
        float v = 0.f;
        if (ch < 64) { if (e < 192) v = Wts[e * 64 + ch]; }
        else if (ch < 80) { if (e >= 192) v = Waux[(e - 192) * 16 + (ch - 64)]; }
        W2[idx] = f2bf(v);
        if (idx < 256) bias2[idx] = idx < 192 ? bts[idx] : baux[idx - 192];
        if (idx < 512) bkv[idx] = idx < 256 ? bk[idx] : bv[idx - 256];
    } else if (bid < 432) {
        int t = (bid - 176) * 2 + (tid >> 8);
        int dd = tid & 255;
        int i = dd >> 1;
        float div = expf((float)(2 * i) * (-9.210340371976184f / 256.0f));
        float ang = (float)t * div;
        pe[t * 256 + dd] = (dd & 1) ? cosf(ang) : sinf(ang);
    } else if (bid < 496) {
        int bn = bid - 432;
        int lane = tid & 63, wid = tid >> 6;
        int m = mask[bn * 512 + tid] != 0;
        int v = m;
#pragma unroll
        for (int off = 1; off < 64; off <<= 1) {
            int t = __shfl_up(v, off);
            if (lane >= off) v += t;
        }
        if (lane == 63) wsum[wid] = v;
        __syncthreads();
        int base = 0;
#pragma unroll
        for (int w = 0; w < 8; ++w) base += (w < wid) ? wsum[w] : 0;
        pos[bn * 512 + tid] = m ? (base + v - 1) : -1;
        if (tid == 511) cnt[bn] = base + v;
    } else {
        int half = tid >> 8;
        int d = tid & 255;
        int row = (bid - 496) * 2 + half;
        int t = row & 511;
        int i = d >> 1;
        float div = expf((float)(2 * i) * (-9.210340371976184f / 256.0f));
        float ang = (float)t * div;
        float pev = (d & 1) ? cosf(ang) : sinf(ang);
        float v = x[(size_t)row * 256 + d] + pev;
        xpe_bf[(size_t)row * 256 + d] = f2bf(v);
        float s = v;
#pragma unroll
        for (int off = 32; off > 0; off >>= 1) s += __shfl_xor(s, off);
        if ((tid & 63) == 0) redA[tid >> 6] = s;
        __syncthreads();
        int rb = half * 4;
        float mu = (redA[rb] + redA[rb + 1] + redA[rb + 2] + redA[rb + 3]) *
                   (1.0f / 256.0f);
        float dv = v - mu;
        float s2 = dv * dv;
#pragma unroll
        for (int off = 32; off > 0; off >>= 1) s2 += __shfl_xor(s2, off);
        if ((tid & 63) == 0) redB[tid >> 6] = s2;
        __syncthreads();
        float var = (redB[rb] + redB[rb + 1] + redB[rb + 2] + redB[rb + 3]) *
                    (1.0f / 255.0f);
        float sd = sqrtf(var);
        qin[(size_t)row * 256 + d] = f2bf(ln_a[d] * dv / (sd + 1e-6f) + ln_b[d]);
    }
}

// ---------------- kv embed as MFMA GEMM over K=96, scatter to compacted rows ----------------
__global__ __launch_bounds__(512, 2) void kv_gemm(
    const float* __restrict__ nbr_ts, const float* __restrict__ nbr_aux,
    const short* __restrict__ W2, const float* __restrict__ bias2,
    const float* __restrict__ pe, const int* __restrict__ pos,
    short* __restrict__ kvc) {
    __shared__ __align__(16) float S1[64 * 132];
    __shared__ __align__(16) float S2[16 * 132];
    __shared__ __align__(16) short A_lds[128 * 104];
    int tid = threadIdx.x;
    int bn = blockIdx.x, l0 = blockIdx.y * 128;
    const float* tsb = nbr_ts + (size_t)bn * 64 * 512;
    const float* axb = nbr_aux + (size_t)bn * 16 * 512;
#pragma unroll
    for (int it = 0; it < 4; ++it) {
        int idx = tid + it * 512;
        int cc = idx >> 5, lq = idx & 31;
        *(float4*)&S1[cc * 132 + lq * 4] =
            *(const float4*)&tsb[(size_t)cc * 512 + l0 + lq * 4];
    }
    {
        int cc = tid >> 5, lq = tid & 31;
        *(float4*)&S2[cc * 132 + lq * 4] =
            *(const float4*)&axb[(size_t)cc * 512 + l0 + lq * 4];
    }
    __syncthreads();
#pragma unroll
    for (int p = 0; p < 3; ++p) {
        int tk = tid + p * 512;
        int l = tk & 127, chunk = tk >> 7;
        union { bf16x8 v; unsigned u[4]; } v8;
        if (chunk < 8) {
#pragma unroll
            for (int i = 0; i < 4; ++i)
                v8.u[i] = pk2bf(S1[(chunk * 8 + 2 * i) * 132 + l],
                                S1[(chunk * 8 + 2 * i + 1) * 132 + l]);
        } else if (chunk < 10) {
#pragma unroll
            for (int i = 0; i < 4; ++i)
                v8.u[i] = pk2bf(S2[((chunk - 8) * 8 + 2 * i) * 132 + l],
                                S2[((chunk - 8) * 8 + 2 * i + 1) * 132 + l]);
        } else {
#pragma unroll
            for (int i = 0; i < 4; ++i) v8.u[i] = 0;
        }
        *(bf16x8*)&A_lds[l * 104 + chunk * 8] = v8.v;
    }
    __syncthreads();
    int wid = tid >> 6, lane = tid & 63;
    int g = lane >> 4, c = lane & 15;
    int lm = wid >> 2, le = wid & 3;
    bf16x8 wf[4][3];
#pragma unroll
    for (int nf = 0; nf < 4; ++nf)
#pragma unroll
        for (int ks = 0; ks < 3; ++ks)
            wf[nf][ks] = *(const bf16x8*)&W2[(size_t)(le * 64 + nf * 16 + c) * 96 +
                                             ks * 32 + g * 8];
    f32x4 acc[4][4];
#pragma unroll
    for (int i = 0; i < 4; ++i)
#pragma unroll
        for (int j = 0; j < 4; ++j) acc[i][j] = (f32x4){0.f, 0.f, 0.f, 0.f};
#pragma unroll
    for (int ks = 0; ks < 3; ++ks) {
#pragma unroll
        for (int mf = 0; mf < 4; ++mf) {
            bf16x8 af = *(const bf16x8*)&A_lds[(lm * 64 + mf * 16 + c) * 104 +
                                               ks * 32 + g * 8];
#pragma unroll
            for (int nf = 0; nf < 4; ++nf)
                acc[mf][nf] = __builtin_amdgcn_mfma_f32_16x16x32_bf16(
                    af, wf[nf][ks], acc[mf][nf], 0, 0, 0);
        }
    }
    float b2c[4];
#pragma unroll
    for (int nf = 0; nf < 4; ++nf) b2c[nf] = bias2[le * 64 + nf * 16 + c];
    short* kvb = kvc + (size_t)bn * 512 * 256;
    const int* posb = pos + bn * 512 + l0;
#pragma unroll
    for (int mf = 0; mf < 4; ++mf) {
#pragma unroll
        for (int r = 0; r < 4; ++r) {
            int lr = lm * 64 + mf * 16 + g * 4 + r;
            int p = posb[lr];
            if (p >= 0) {
#pragma unroll
                for (int nf = 0; nf < 4; ++nf) {
                    int e = le * 64 + nf * 16 + c;
                    kvb[(size_t)p * 256 + e] =
                        f2bf(acc[mf][nf][r] + b2c[nf] +
                             pe[(size_t)(l0 + lr) * 256 + e]);
                }
            }
        }
    }
}

// ---------------- merged q-projection + compact K|V projection ----------------
__global__ __launch_bounds__(256) void proj_gemm(
    const short* __restrict__ qin, const short* __restrict__ kvc,
    const short* __restrict__ wq, const short* __restrict__ wkv,
    const float* __restrict__ bq, const float* __restrict__ bkv,
    const int* __restrict__ cnt, short* __restrict__ qout,
    short* __restrict__ kv2) {
    int bx = blockIdx.x;
    const short* A; const short* Wm; const float* bias; short* C;
    int row0, col0, LDC; float esc;
    if (bx < 64) {
        row0 = (bx >> 1) * 128; col0 = (bx & 1) * 128;
        A = qin; Wm = wq; bias = bq; C = qout; LDC = 256; esc = SCALE2;
    } else {
        int idx = bx - 64;               // 1024 = bn(64) x mt(4) x ct(4)
        int bn = idx >> 4, mt = (idx >> 2) & 3, ct = idx & 3;
        int nvp = (cnt[bn] + 15) & ~15;
        row0 = mt * 128;
        if (row0 >= nvp) return;
        col0 = ct * 128;
        A = kvc + (size_t)bn * 512 * 256; Wm = wkv; bias = bkv;
        C = kv2 + (size_t)bn * 512 * 512; LDC = 512; esc = 1.0f;
    }
    __shared__ __align__(16) short As[128 * 40];
    __shared__ __align__(16) short Bs[128 * 40];
    int tid = threadIdx.x;
    int wid = tid >> 6, lane = tid & 63;
    int wm = wid >> 1, wn = wid & 1;
    int g = lane >> 4, c = lane & 15;
    f32x4 acc[4][4];
#pragma unroll
    for (int i = 0; i < 4; ++i)
#pragma unroll
        for (int j = 0; j < 4; ++j) acc[i][j] = (f32x4){0.f, 0.f, 0.f, 0.f};

    for (int k0 = 0; k0 < 256; k0 += 32) {
#pragma unroll
        for (int it = 0; it < 2; ++it) {
            int idx = tid + it * 256;
            int r = idx >> 2, ch = idx & 3;
            *(bf16x8*)&As[r * 40 + ch * 8] =
                *(const bf16x8*)&A[(size_t)(row0 + r) * 256 + k0 + ch * 8];
            *(bf16x8*)&Bs[r * 40 + ch * 8] =
                *(const bf16x8*)&Wm[(size_t)(col0 + r) * 256 + k0 + ch * 8];
        }
        __syncthreads();
        bf16x8 af[4], bfr[4];
#pragma unroll
        for (int mf = 0; mf < 4; ++mf)
            af[mf] = *(const bf16x8*)&As[(wm * 64 + mf * 16 + c) * 40 + g * 8];
#pragma unroll
        for (int nf = 0; nf < 4; ++nf)
            bfr[nf] = *(const bf16x8*)&Bs[(wn * 64 + nf * 16 + c) * 40 + g * 8];
#pragma unroll
        for (int mf = 0; mf < 4; ++mf)
#pragma unroll
            for (int nf = 0; nf < 4; ++nf)
                acc[mf][nf] = __builtin_amdgcn_mfma_f32_16x16x32_bf16(
                    af[mf], bfr[nf], acc[mf][nf], 0, 0, 0);
        __syncthreads();
    }
#pragma unroll
    for (int nf = 0; nf < 4; ++nf) {
        int col = col0 + wn * 64 + nf * 16 + c;
        float bz = bias[col];
#pragma unroll
        for (int mf = 0; mf < 4; ++mf)
#pragma unroll
            for (int r = 0; r < 4; ++r) {
                int row = row0 + wm * 64 + mf * 16 + g * 4 + r;
                C[(size_t)row * LDC + col] = f2bf((acc[mf][nf][r] + bz) * esc);
            }
    }
}

// ---------------- fused MFMA attention per (b,n,h), compacted K/V ----------------
template <bool MASKED>
__device__ __forceinline__ void attn_step(
    const short* K_lds, const short* Vt_lds, const bf16x8* qf,
    f32x4 (*ctxa)[2], f32x4* rsv, int l0, int nv, int g, int c) {
    bf16x8 ak = *(const bf16x8*)&K_lds[(l0 + c) * 40 + g * 8];
    bf16x4 vb0 = *(const bf16x4*)&Vt_lds[c * 524 + l0 + g * 4];
    bf16x4 vb1 = *(const bf16x4*)&Vt_lds[(16 + c) * 524 + l0 + g * 4];
    int lb = l0 + g * 4;
#pragma unroll
    for (int tf = 0; tf < 4; ++tf) {
        f32x4 s = __builtin_amdgcn_mfma_f32_16x16x32_bf16(
            ak, qf[tf], (f32x4){0.f, 0.f, 0.f, 0.f}, 0, 0, 0);
        float p0 = exp2f(s[0]);
        float p1 = exp2f(s[1]);
        float p2 = exp2f(s[2]);
        float p3 = exp2f(s[3]);
        if (MASKED) {
            p0 = (lb + 0 < nv) ? p0 : 0.f;
            p1 = (lb + 1 < nv) ? p1 : 0.f;
            p2 = (lb + 2 < nv) ? p2 : 0.f;
            p3 = (lb + 3 < nv) ? p3 : 0.f;
        }
        rsv[tf] += (f32x4){p0, p1, p2, p3};
        union { bf16x4 v; unsigned u[2]; } pu;
        pu.u[0] = pk2bf(p0, p1);
        pu.u[1] = pk2bf(p2, p3);
        __builtin_amdgcn_s_setprio(1);
        ctxa[tf][0] = mfma16(pu.v, vb0, ctxa[tf][0]);
        ctxa[tf][1] = mfma16(pu.v, vb1, ctxa[tf][1]);
        __builtin_amdgcn_s_setprio(0);
    }
}

__global__ __launch_bounds__(512, 2) void attn_kernel(
    const short* __restrict__ Q, const short* __restrict__ KV2,
    const int* __restrict__ cnt, short* __restrict__ ctx) {
    __shared__ __align__(16) short K_lds[512 * 40];
    __shared__ __align__(16) short Vt_lds[32 * 524];
    int tid = threadIdx.x;
    int bx = blockIdx.x;
    int h = bx & 7, bn = bx >> 3, b = bn >> 3;
    int nv = cnt[bn];
    int nvp = (nv + 15) & ~15;
    const short* kvr = KV2 + (size_t)bn * 512 * 512 + h * 32;
#pragma unroll
    for (int it = 0; it < 4; ++it) {
        int idx = tid + it * 512;
        int i = idx >> 2, ch = idx & 3;
        if (i < nvp) {
            bf16x8 kval = (bf16x8){0, 0, 0, 0, 0, 0, 0, 0};
            bf16x8 vval = (bf16x8){0, 0, 0, 0, 0, 0, 0, 0};
            if (i < nv) {
                kval = *(const bf16x8*)&kvr[(size_t)i * 512 + ch * 8];
                vval = *(const bf16x8*)&kvr[(size_t)i * 512 + 256 + ch * 8];
            }
            *(bf16x8*)&K_lds[i * 40 + ch * 8] = kval;
#pragma unroll
            for (int k = 0; k < 8; ++k)
                Vt_lds[(ch * 8 + k) * 524 + i] = vval[k];
        }
    }
    __syncthreads();

    int wid = tid >> 6, lane = tid & 63;
    int g = lane >> 4, c = lane & 15;
    int t0 = wid * 64;
    const short* qg = Q + ((size_t)b * 512 + t0 + c) * 256 + h * 32 + g * 8;
    bf16x8 qf[4];
#pragma unroll
    for (int tf = 0; tf < 4; ++tf)
        qf[tf] = *(const bf16x8*)&qg[(size_t)tf * 16 * 256];

    f32x4 ctxa[4][2];
    f32x4 rsv[4];
#pragma unroll
    for (int tf = 0; tf < 4; ++tf) {
        ctxa[tf][0] = (f32x4){0.f, 0.f, 0.f, 0.f};
        ctxa[tf][1] = (f32x4){0.f, 0.f, 0.f, 0.f};
        rsv[tf] = (f32x4){0.f, 0.f, 0.f, 0.f};
    }
    int nfull = nv & ~15;
    for (int l0 = 0; l0 < nfull; l0 += 16)
        attn_step<false>(K_lds, Vt_lds, qf, ctxa, rsv, l0, nv, g, c);
    if (nfull < nvp)
        attn_step<true>(K_lds, Vt_lds, qf, ctxa, rsv, nfull, nv, g, c);
#ifndef HAVE_MFMA16
    asm volatile("s_nop 7\ns_nop 7");
#endif
#pragma unroll
    for (int tf = 0; tf < 4; ++tf) {
        float r = (rsv[tf][0] + rsv[tf][1]) + (rsv[tf][2] + rsv[tf][3]);
        r += __shfl_xor(r, 16);
        r += __shfl_xor(r, 32);
        float inv = 1.f / r;   // rowsum for t-row = c, replicated over groups
#pragma unroll
        for (int rr = 0; rr < 4; ++rr) {
            float invr = __shfl(inv, (lane & 48) | (g * 4 + rr));
            ctxa[tf][0][rr] *= invr;
            ctxa[tf][1][rr] *= invr;
        }
    }
    __syncthreads();   // all waves done with K_lds/Vt_lds; reuse K_lds as staging
#pragma unroll
    for (int tf = 0; tf < 4; ++tf)
#pragma unroll
        for (int df = 0; df < 2; ++df)
#pragma unroll
            for (int rr = 0; rr < 4; ++rr)
                K_lds[(t0 + tf * 16 + g * 4 + rr) * 40 + df * 16 + c] =
                    f2bf(ctxa[tf][df][rr]);
    __syncthreads();
    short* cg = ctx + (size_t)bn * 512 * 256 + h * 32;
#pragma unroll
    for (int it = 0; it < 4; ++it) {
        int idx = tid + it * 512;
        int l = idx >> 2, ch = idx & 3;
        *(bf16x8*)&cg[(size_t)l * 256 + ch * 8] =
            *(const bf16x8*)&K_lds[l * 40 + ch * 8];
    }
}

// ---------------- fused Wo-GEMM + edge + mean_n ----------------
// block = (b, t-tile of 32, d-tile of 64); loops n as reduction.
// out[b,t,d] = (1/8) sum_n (xpe[b,t,d] + (ctx_n @ Wo^T)[t,d] + bo[d]) * edge_n[t,d]
__global__ __launch_bounds__(256, 3) void wo_final(
    const short* __restrict__ ctx, const short* __restrict__ wo,
    const float* __restrict__ bo, const short* __restrict__ xpe,
    const float* __restrict__ nbr_edge, const float* __restrict__ Wedge,
    const float* __restrict__ bedge, float* __restrict__ out) {
    __shared__ __align__(16) short Ws[64 * 264];
    __shared__ __align__(16) short As[32 * 264];
    __shared__ __align__(16) float edge_s[8][36];
    int bx = blockIdx.x;
    int b = bx >> 6, tt = (bx >> 2) & 15, dt = bx & 3;
    int t0 = tt * 32, d0 = dt * 64;
    int tid = threadIdx.x;
    int wid = tid >> 6, lane = tid & 63;
    int th = wid & 1, dh = wid >> 1;
    int g = lane >> 4, c = lane & 15;

    // stage Wo slice [d0, d0+64) x 256 once
#pragma unroll
    for (int it = 0; it < 8; ++it) {
        int idx = tid + it * 256;
        int r = idx >> 5, kk = (idx & 31) * 8;
        *(bf16x8*)&Ws[r * 264 + kk] =
            *(const bf16x8*)&wo[(size_t)(d0 + r) * 256 + kk];
    }
    // per-thread constants
    int trloc = th * 16 + g * 4;               // local t row base (4 rows)
    int dcol[2];
    float we[2][8], be[2], xb[2][4];
#pragma unroll
    for (int j = 0; j < 2; ++j) {
        dcol[j] = d0 + dh * 32 + j * 16 + c;
#pragma unroll
        for (int cc = 0; cc < 8; ++cc) we[j][cc] = Wedge[dcol[j] * 8 + cc];
        be[j] = bedge[dcol[j]];
        float boj = bo[dcol[j]];
#pragma unroll
        for (int r = 0; r < 4; ++r)
            xb[j][r] = bf2f(xpe[((size_t)b * 512 + t0 + trloc + r) * 256 +
                                dcol[j]]) + boj;
    }
    f32x4 oacc[2] = {(f32x4){0.f, 0.f, 0.f, 0.f}, (f32x4){0.f, 0.f, 0.f, 0.f}};

    for (int n = 0; n < 8; ++n) {
        int bn = b * 8 + n;
#pragma unroll
        for (int it = 0; it < 4; ++it) {
            int idx = tid + it * 256;
            int r = idx >> 5, kk = (idx & 31) * 8;
            *(bf16x8*)&As[r * 264 + kk] =
                *(const bf16x8*)&ctx[((size_t)bn * 512 + t0 + r) * 256 + kk];
        }
        {
            int cc = tid >> 5, tl = tid & 31;
            edge_s[cc][tl] = nbr_edge[((size_t)bn * 8 + cc) * 512 + t0 + tl];
        }
        __syncthreads();
        f32x4 acc[2] = {(f32x4){0.f, 0.f, 0.f, 0.f},
                        (f32x4){0.f, 0.f, 0.f, 0.f}};
#pragma unroll
        for (int k0 = 0; k0 < 8; ++k0) {
            bf16x8 af = *(const bf16x8*)&As[(th * 16 + c) * 264 + k0 * 32 + g * 8];
#pragma unroll
            for (int j = 0; j < 2; ++j) {
                bf16x8 bf = *(const bf16x8*)&Ws[(dh * 32 + j * 16 + c) * 264 +
                                                k0 * 32 + g * 8];
                acc[j] = __builtin_amdgcn_mfma_f32_16x16x32_bf16(af, bf, acc[j],
                                                                 0, 0, 0);
            }
        }
#pragma unroll
        for (int j = 0; j < 2; ++j)
#pragma unroll
            for (int r = 0; r < 4; ++r) {
                float e = be[j];
#pragma unroll
                for (int cc = 0; cc < 8; ++cc)
                    e = fmaf(edge_s[cc][trloc + r], we[j][cc], e);
                oacc[j][r] = fmaf(acc[j][r] + xb[j][r], e, oacc[j][r]);
            }
        __syncthreads();
    }
#pragma unroll
    for (int j = 0; j < 2; ++j)
#pragma unroll
        for (int r = 0; r < 4; ++r)
            out[((size_t)b * 512 + t0 + trloc + r) * 256 + dcol[j]] =
                oacc[j][r] * 0.125f;
}

extern "C" void kernel_launch(void* const* d_in, const int* in_sizes, int n_in,
                              void* d_out, int out_size, void* d_ws, size_t ws_size,
                              hipStream_t stream) {
    const float* x        = (const float*)d_in[0];
    const float* nbr_ts   = (const float*)d_in[1];
    const float* nbr_aux  = (const float*)d_in[2];
    const float* nbr_edge = (const float*)d_in[3];
    const int*   mask     = (const int*)d_in[4];
    const float* Wts  = (const float*)d_in[5];
    const float* bts  = (const float*)d_in[6];
    const float* Waux = (const float*)d_in[7];
    const float* baux = (const float*)d_in[8];
    const float* Wedge= (const float*)d_in[9];
    const float* bedge= (const float*)d_in[10];
    const float* ln_a = (const float*)d_in[11];
    const float* ln_b = (const float*)d_in[12];
    const float* Wq = (const float*)d_in[13];
    const float* bq = (const float*)d_in[14];
    const float* Wk = (const float*)d_in[15];
    const float* bk = (const float*)d_in[16];
    const float* Wv = (const float*)d_in[17];
    const float* bv = (const float*)d_in[18];
    const float* Wo = (const float*)d_in[19];
    const float* bo = (const float*)d_in[20];
    float* out = (float*)d_out;

    char* W = (char*)d_ws;
    float* pe_f    = (float*)(W);                 // 512 KB
    short* xpe_bf  = (short*)(W + 524288);        // 2 MB
    short* qin_bf  = (short*)(W + 4718592);       // 2 MB
    short* q_bf    = (short*)(W + 6815744);       // 2 MB
    short* kvc_bf  = (short*)(W + 8912896);       // 16 MB (compacted kv embed)
    short* kv2c_bf = (short*)(W + 25690112);      // 32 MB (compacted K|V, LDC 512)
    short* ctx_bf  = (short*)(W + 59244544);      // 16 MB
    short* w_bf    = (short*)(W + 92798976);      // 512 KB
    short* W2_bf   = (short*)(W + 93323264);      // 48 KB
    float* bias2_f = (float*)(W + 93372416);      // 1 KB
    float* bkv_f   = (float*)(W + 93373440);      // 2 KB
    int*   pos     = (int*)  (W + 93375488);      // 128 KB
    int*   cnt     = (int*)  (W + 93506560);      // 256 B
    short* wq_bf = w_bf;
    short* wkv_bf = w_bf + 65536;  // wk,wv contiguous => one [512][256] matrix
    short* wo_bf = w_bf + 196608;

    setup_kernel<<<2544, 512, 0, stream>>>(
        Wq, Wk, Wv, Wo, Wts, Waux, bts, baux, bk, bv, x, ln_a, ln_b, mask,
        w_bf, W2_bf, bias2_f, bkv_f, pe_f, pos, cnt, xpe_bf, qin_bf);
    kv_gemm<<<dim3(64, 4), 512, 0, stream>>>(nbr_ts, nbr_aux, W2_bf, bias2_f,
                                             pe_f, pos, kvc_bf);
    proj_gemm<<<1088, 256, 0, stream>>>(qin_bf, kvc_bf, wq_bf, wkv_bf, bq,
                                        bkv_f, cnt, q_bf, kv2c_bf);
    attn_kernel<<<512, 512, 0, stream>>>(q_bf, kv2c_bf, cnt, ctx_bf);
    wo_final<<<512, 256, 0, stream>>>(ctx_bf, wo_bf, bo, xpe_bf, nbr_edge,
                                      Wedge, bedge, out);
}